// Round 1
// baseline (4911.385 us; speedup 1.0000x reference)
//
#include <hip/hip_runtime.h>
#include <cmath>

#define S_LEN 4096
#define DMODEL 768
#define NHEAD 12
#define DHEAD 64
#define FFDIM 3072
#define NLAYER 12
#define WINR 256

typedef float f32x4 __attribute__((ext_vector_type(4)));
typedef short s4v __attribute__((ext_vector_type(4)));
typedef short s8v __attribute__((ext_vector_type(8)));
typedef __bf16 b8v __attribute__((ext_vector_type(8)));

__device__ __forceinline__ short f2b(float f) {
  unsigned u = __builtin_bit_cast(unsigned, f);
  unsigned r = (u + 0x7fffu + ((u >> 16) & 1u)) >> 16;
  return (short)r;
}

__device__ __forceinline__ f32x4 mfma16(s8v a, s8v b, f32x4 c) {
  return __builtin_amdgcn_mfma_f32_16x16x32_bf16(
      __builtin_bit_cast(b8v, a), __builtin_bit_cast(b8v, b), c, 0, 0, 0);
}

__device__ __forceinline__ s8v cat8(s4v a, s4v b) {
  s8v r;
  r[0] = a[0]; r[1] = a[1]; r[2] = a[2]; r[3] = a[3];
  r[4] = b[0]; r[5] = b[1]; r[6] = b[2]; r[7] = b[3];
  return r;
}

__device__ __forceinline__ s4v cvt4(float4 f) {
  s4v v; v[0] = f2b(f.x); v[1] = f2b(f.y); v[2] = f2b(f.z); v[3] = f2b(f.w);
  return v;
}

// ---------------------------------------------------------------------------
// Generic GEMM: C[4096,N] = A[4096,K] @ B[K,N] + bias, f32 in/out, bf16 MFMA.
// EPI: 0 = none, 1 = exact GELU, 2 = QKV (scale by 1/8 when blockIdx.z == 0)
// grid = (N/128, 32, Z); block = 256.
// ---------------------------------------------------------------------------
template <int EPI>
__global__ __launch_bounds__(256) void gemm_kernel(
    const float* __restrict__ A, const float* __restrict__ B,
    const float* __restrict__ bias, float* __restrict__ C,
    int N, int K, long sB, long sBias, long sC) {
  __shared__ short As[128][36];   // [m][k], stride 36 shorts (72B, 8B-aligned)
  __shared__ short Bs[32][132];   // [k][n], stride 132 shorts (264B)

  const int t = threadIdx.x;
  const int lane = t & 63;
  const int w = t >> 6;
  const int lo = lane & 15, hi = lane >> 4;
  const int wm = (w >> 1) * 64, wn = (w & 1) * 64;
  const long bm = (long)blockIdx.y * 128;
  const int bn = blockIdx.x * 128;
  const int z = blockIdx.z;
  B += (long)z * sB;
  bias += (long)z * sBias;
  C += (long)z * sC;

  f32x4 acc[4][4];
#pragma unroll
  for (int i = 0; i < 4; ++i)
#pragma unroll
    for (int j = 0; j < 4; ++j) {
      f32x4 zz = {0.f, 0.f, 0.f, 0.f};
      acc[i][j] = zz;
    }

  for (int k0 = 0; k0 < K; k0 += 32) {
    __syncthreads();
    {  // stage A tile (128x32), f32 -> bf16
      int row = t >> 2;
      int kc = (t & 3) * 8;
#pragma unroll
      for (int r = 0; r < 2; ++r) {
        const float* p = A + (bm + row) * (long)K + k0 + kc;
        float4 f0 = *(const float4*)p;
        float4 f1 = *(const float4*)(p + 4);
        *(s4v*)&As[row][kc] = cvt4(f0);
        *(s4v*)&As[row][kc + 4] = cvt4(f1);
        row += 64;
      }
    }
    {  // stage B tile (32x128), f32 -> bf16
      int k = t >> 3;
      int nc = (t & 7) * 16;
      const float* p = B + (long)(k0 + k) * N + bn + nc;
#pragma unroll
      for (int q = 0; q < 4; ++q) {
        float4 f = *(const float4*)(p + q * 4);
        *(s4v*)&Bs[k][nc + q * 4] = cvt4(f);
      }
    }
    __syncthreads();

    s8v af[4], bf[4];
#pragma unroll
    for (int mi = 0; mi < 4; ++mi) {
      const short* pr = &As[wm + mi * 16 + lo][hi * 8];
      af[mi] = cat8(*(const s4v*)pr, *(const s4v*)(pr + 4));
    }
#pragma unroll
    for (int ni = 0; ni < 4; ++ni) {
      int col = wn + ni * 16 + lo;
      s8v bv;
#pragma unroll
      for (int j = 0; j < 8; ++j) bv[j] = Bs[hi * 8 + j][col];
      bf[ni] = bv;
    }
#pragma unroll
    for (int mi = 0; mi < 4; ++mi)
#pragma unroll
      for (int ni = 0; ni < 4; ++ni)
        acc[mi][ni] = mfma16(af[mi], bf[ni], acc[mi][ni]);
  }

  const float sc = (EPI == 2 && z == 0) ? 0.125f : 1.0f;
#pragma unroll
  for (int mi = 0; mi < 4; ++mi)
#pragma unroll
    for (int ni = 0; ni < 4; ++ni) {
      int col = bn + wn + ni * 16 + lo;
      float bb = bias[col];
#pragma unroll
      for (int jj = 0; jj < 4; ++jj) {
        long row = bm + wm + mi * 16 + hi * 4 + jj;
        float v = (acc[mi][ni][jj] + bb) * sc;
        if (EPI == 1) v = 0.5f * v * (1.0f + erff(v * 0.7071067811865476f));
        C[row * N + col] = v;
      }
    }
}

// ---------------------------------------------------------------------------
// Banded flash attention: grid = (16 qblocks, 12 heads), block = 256 (4 waves,
// 64 q-rows each). K/V tiles of 32 keys staged in LDS; online softmax.
// Q is pre-scaled by 1/8 in the QKV GEMM epilogue.
// ---------------------------------------------------------------------------
__global__ __launch_bounds__(256) void attn_kernel(
    const float* __restrict__ Qb, const float* __restrict__ Kb,
    const float* __restrict__ Vb, const int* __restrict__ maskp,
    float* __restrict__ Ob) {
  __shared__ short Ks[32][72];      // [key][d]
  __shared__ short VT[64][36];      // [d][key]
  __shared__ short Pl[4][64][36];   // per-wave P tile [q][key]

  const int t = threadIdx.x;
  const int lane = t & 63;
  const int w = t >> 6;
  const int lo = lane & 15, hi = lane >> 4;
  const int nq = blockIdx.x, h = blockIdx.y;
  const int qbase = nq * 256 + w * 64;

  // Q fragments (stay in registers for the whole block)
  s8v aq[4][2];
#pragma unroll
  for (int mi = 0; mi < 4; ++mi)
#pragma unroll
    for (int kg = 0; kg < 2; ++kg) {
      const float* p =
          Qb + (long)(qbase + mi * 16 + lo) * DMODEL + h * 64 + kg * 32 + hi * 8;
      float4 f0 = *(const float4*)p;
      float4 f1 = *(const float4*)(p + 4);
      aq[mi][kg] = cat8(cvt4(f0), cvt4(f1));
    }

  f32x4 o[4][4];
#pragma unroll
  for (int i = 0; i < 4; ++i)
#pragma unroll
    for (int j = 0; j < 4; ++j) {
      f32x4 zz = {0.f, 0.f, 0.f, 0.f};
      o[i][j] = zz;
    }
  float rm[16], rl[16];
#pragma unroll
  for (int r = 0; r < 16; ++r) { rm[r] = -1e30f; rl[r] = 0.f; }

  const int kstart = max(0, (nq - 1) * WINR);
  const int kend = min(S_LEN, (nq + 2) * WINR);

  for (int kt = kstart; kt < kend; kt += 32) {
    __syncthreads();
    {  // stage K tile and V^T tile
      int key = t >> 3;
      int dc = (t & 7) * 8;
      const float* pk = Kb + (long)(kt + key) * DMODEL + h * 64 + dc;
      float4 f0 = *(const float4*)pk;
      float4 f1 = *(const float4*)(pk + 4);
      *(s4v*)&Ks[key][dc] = cvt4(f0);
      *(s4v*)&Ks[key][dc + 4] = cvt4(f1);
      const float* pv = Vb + (long)(kt + key) * DMODEL + h * 64 + dc;
      float4 g0 = *(const float4*)pv;
      float4 g1 = *(const float4*)(pv + 4);
      float gv[8] = {g0.x, g0.y, g0.z, g0.w, g1.x, g1.y, g1.z, g1.w};
#pragma unroll
      for (int j = 0; j < 8; ++j) VT[dc + j][key] = f2b(gv[j]);
    }
    __syncthreads();

    // S = Q K^T for this 64x32 tile
    f32x4 sacc[4][2];
#pragma unroll
    for (int i = 0; i < 4; ++i)
#pragma unroll
      for (int j = 0; j < 2; ++j) {
        f32x4 zz = {0.f, 0.f, 0.f, 0.f};
        sacc[i][j] = zz;
      }
    s8v bk[2][2];
#pragma unroll
    for (int ni = 0; ni < 2; ++ni)
#pragma unroll
      for (int kg = 0; kg < 2; ++kg) {
        const short* pr = &Ks[ni * 16 + lo][kg * 32 + hi * 8];
        bk[ni][kg] = cat8(*(const s4v*)pr, *(const s4v*)(pr + 4));
      }
#pragma unroll
    for (int mi = 0; mi < 4; ++mi)
#pragma unroll
      for (int ni = 0; ni < 2; ++ni) {
        sacc[mi][ni] = mfma16(aq[mi][0], bk[ni][0], sacc[mi][ni]);
        sacc[mi][ni] = mfma16(aq[mi][1], bk[ni][1], sacc[mi][ni]);
      }

    int mval[2];
#pragma unroll
    for (int ni = 0; ni < 2; ++ni) mval[ni] = maskp[kt + ni * 16 + lo];

    // online softmax update
#pragma unroll
    for (int mi = 0; mi < 4; ++mi) {
#pragma unroll
      for (int jj = 0; jj < 4; ++jj) {
        const int qg = qbase + mi * 16 + hi * 4 + jj;
        float m0 = -1e30f;
#pragma unroll
        for (int ni = 0; ni < 2; ++ni) {
          int kg = kt + ni * 16 + lo;
          bool val = (kg >= qg - WINR) && (kg <= qg + WINR) && (mval[ni] != 0);
          float sv = val ? sacc[mi][ni][jj] : -1e30f;
          sacc[mi][ni][jj] = sv;
          m0 = fmaxf(m0, sv);
        }
        m0 = fmaxf(m0, __shfl_xor(m0, 1));
        m0 = fmaxf(m0, __shfl_xor(m0, 2));
        m0 = fmaxf(m0, __shfl_xor(m0, 4));
        m0 = fmaxf(m0, __shfl_xor(m0, 8));
        const int r = mi * 4 + jj;
        float mnew = fmaxf(rm[r], m0);
        float scl = __expf(rm[r] - mnew);
        rm[r] = mnew;
        float ts = 0.f;
#pragma unroll
        for (int ni = 0; ni < 2; ++ni) {
          float sv = sacc[mi][ni][jj];
          float p = (sv > -1e29f) ? __expf(sv - mnew) : 0.f;
          sacc[mi][ni][jj] = p;
          ts += p;
        }
        ts += __shfl_xor(ts, 1);
        ts += __shfl_xor(ts, 2);
        ts += __shfl_xor(ts, 4);
        ts += __shfl_xor(ts, 8);
        rl[r] = rl[r] * scl + ts;
#pragma unroll
        for (int di = 0; di < 4; ++di) o[mi][di][jj] *= scl;
      }
    }

    // P -> LDS (bf16)
#pragma unroll
    for (int mi = 0; mi < 4; ++mi)
#pragma unroll
      for (int jj = 0; jj < 4; ++jj)
#pragma unroll
        for (int ni = 0; ni < 2; ++ni)
          Pl[w][mi * 16 + hi * 4 + jj][ni * 16 + lo] = f2b(sacc[mi][ni][jj]);
    __syncthreads();

    // O += P @ V
    s8v ap[4], bv[4];
#pragma unroll
    for (int mi = 0; mi < 4; ++mi) {
      const short* pr = &Pl[w][mi * 16 + lo][hi * 8];
      ap[mi] = cat8(*(const s4v*)pr, *(const s4v*)(pr + 4));
    }
#pragma unroll
    for (int di = 0; di < 4; ++di) {
      const short* pr = &VT[di * 16 + lo][hi * 8];
      bv[di] = cat8(*(const s4v*)pr, *(const s4v*)(pr + 4));
    }
#pragma unroll
    for (int mi = 0; mi < 4; ++mi)
#pragma unroll
      for (int di = 0; di < 4; ++di)
        o[mi][di] = mfma16(ap[mi], bv[di], o[mi][di]);
  }

  // write normalized output
#pragma unroll
  for (int mi = 0; mi < 4; ++mi)
#pragma unroll
    for (int di = 0; di < 4; ++di)
#pragma unroll
      for (int jj = 0; jj < 4; ++jj) {
        const int r = mi * 4 + jj;
        long row = qbase + mi * 16 + hi * 4 + jj;
        Ob[row * DMODEL + h * 64 + di * 16 + lo] = o[mi][di][jj] / rl[r];
      }
}

// ---------------------------------------------------------------------------
// Embedding + LayerNorm. grid = 4096, block = 256.
// ---------------------------------------------------------------------------
__global__ __launch_bounds__(256) void embed_ln_kernel(
    const int* __restrict__ tok, const float* __restrict__ wemb,
    const float* __restrict__ pemb, const float* __restrict__ gs,
    const float* __restrict__ gb, float* __restrict__ X) {
  __shared__ float sm1[4], sm2[4];
  const int row = blockIdx.x;
  const int tk = tok[row];
  float v[3];
  float s = 0.f, q = 0.f;
#pragma unroll
  for (int i = 0; i < 3; ++i) {
    int c = threadIdx.x + i * 256;
    float x = wemb[(long)tk * DMODEL + c] + pemb[(long)(row + 2) * DMODEL + c];
    v[i] = x;
    s += x;
    q += x * x;
  }
#pragma unroll
  for (int off = 32; off; off >>= 1) {
    s += __shfl_down(s, off);
    q += __shfl_down(q, off);
  }
  int w = threadIdx.x >> 6;
  if ((threadIdx.x & 63) == 0) { sm1[w] = s; sm2[w] = q; }
  __syncthreads();
  s = sm1[0] + sm1[1] + sm1[2] + sm1[3];
  q = sm2[0] + sm2[1] + sm2[2] + sm2[3];
  float mu = s * (1.f / DMODEL);
  float var = q * (1.f / DMODEL) - mu * mu;
  float inv = rsqrtf(var + 1e-5f);
#pragma unroll
  for (int i = 0; i < 3; ++i) {
    int c = threadIdx.x + i * 256;
    X[(long)row * DMODEL + c] = (v[i] - mu) * inv * gs[c] + gb[c];
  }
}

// ---------------------------------------------------------------------------
// X = LayerNorm(X + T). grid = 4096, block = 256.
// ---------------------------------------------------------------------------
__global__ __launch_bounds__(256) void resln_kernel(
    float* __restrict__ X, const float* __restrict__ T,
    const float* __restrict__ gs, const float* __restrict__ gb) {
  __shared__ float sm1[4], sm2[4];
  const int row = blockIdx.x;
  float v[3];
  float s = 0.f, q = 0.f;
#pragma unroll
  for (int i = 0; i < 3; ++i) {
    int c = threadIdx.x + i * 256;
    float x = X[(long)row * DMODEL + c] + T[(long)row * DMODEL + c];
    v[i] = x;
    s += x;
    q += x * x;
  }
#pragma unroll
  for (int off = 32; off; off >>= 1) {
    s += __shfl_down(s, off);
    q += __shfl_down(q, off);
  }
  int w = threadIdx.x >> 6;
  if ((threadIdx.x & 63) == 0) { sm1[w] = s; sm2[w] = q; }
  __syncthreads();
  s = sm1[0] + sm1[1] + sm1[2] + sm1[3];
  q = sm2[0] + sm2[1] + sm2[2] + sm2[3];
  float mu = s * (1.f / DMODEL);
  float var = q * (1.f / DMODEL) - mu * mu;
  float inv = rsqrtf(var + 1e-5f);
#pragma unroll
  for (int i = 0; i < 3; ++i) {
    int c = threadIdx.x + i * 256;
    X[(long)row * DMODEL + c] = (v[i] - mu) * inv * gs[c] + gb[c];
  }
}

// ---------------------------------------------------------------------------
// out[row] = dot(H[row,:512], w4[:,0]) + b4[0]. grid = 1024, block = 256.
// ---------------------------------------------------------------------------
__global__ __launch_bounds__(256) void cls_final_kernel(
    const float* __restrict__ Hh, const float* __restrict__ w4,
    const float* __restrict__ b4, float* __restrict__ out) {
  const int w = threadIdx.x >> 6, lane = threadIdx.x & 63;
  const int row = blockIdx.x * 4 + w;
  float s = 0.f;
#pragma unroll
  for (int j = 0; j < 8; ++j) {
    int k = lane + j * 64;
    s += Hh[(long)row * 512 + k] * w4[k * 2];
  }
#pragma unroll
  for (int off = 32; off; off >>= 1) s += __shfl_down(s, off);
  if (lane == 0) out[row] = s + b4[0];
}

// ---------------------------------------------------------------------------
extern "C" void kernel_launch(void* const* d_in, const int* in_sizes, int n_in,
                              void* d_out, int out_size, void* d_ws,
                              size_t ws_size, hipStream_t stream) {
  const int* essay = (const int*)d_in[0];
  const float* wemb = (const float*)d_in[1];
  const float* pemb = (const float*)d_in[2];
  const float* eln_s = (const float*)d_in[3];
  const float* eln_b = (const float*)d_in[4];
  const float* qkv_w = (const float*)d_in[5];
  const float* qkv_b = (const float*)d_in[6];
  const float* aow = (const float*)d_in[7];
  const float* aob = (const float*)d_in[8];
  const float* aln_s = (const float*)d_in[9];
  const float* aln_b = (const float*)d_in[10];
  const float* w1 = (const float*)d_in[11];
  const float* b1 = (const float*)d_in[12];
  const float* w2 = (const float*)d_in[13];
  const float* b2 = (const float*)d_in[14];
  const float* fln_s = (const float*)d_in[15];
  const float* fln_b = (const float*)d_in[16];
  const float* c1w = (const float*)d_in[17];
  const float* c1b = (const float*)d_in[18];
  const float* c2w = (const float*)d_in[19];
  const float* c2b = (const float*)d_in[20];
  const float* c3w = (const float*)d_in[21];
  const float* c3b = (const float*)d_in[22];
  const float* c4w = (const float*)d_in[23];
  const float* c4b = (const float*)d_in[24];

  const long SD = (long)S_LEN * DMODEL;             // 3,145,728 floats
  const long needed = (6 * SD + (long)S_LEN * FFDIM) * 4;
  if (ws_size < (size_t)needed) return;  // fail cleanly rather than corrupt

  float* ws = (float*)d_ws;
  float* X = ws;                 // [S, DM]
  float* QKV = ws + SD;          // 3 x [S, DM]
  float* T1 = ws + 4 * SD;       // attention output
  float* T3 = ws + 5 * SD;       // projection temp
  float* T2 = ws + 6 * SD;       // FFN intermediate [S, FF]
  float* H1 = QKV;               // classifier reuse [S,512]
  float* H2 = QKV + SD;
  float* H3 = QKV + 2 * SD;
  const int* maskp = essay + S_LEN;

  embed_ln_kernel<<<S_LEN, 256, 0, stream>>>(essay, wemb, pemb, eln_s, eln_b, X);

  for (int l = 0; l < NLAYER; ++l) {
    gemm_kernel<2><<<dim3(6, 32, 3), 256, 0, stream>>>(
        X, qkv_w + (long)l * 3 * DMODEL * DMODEL, qkv_b + (long)l * 3 * DMODEL,
        QKV, DMODEL, DMODEL, (long)DMODEL * DMODEL, DMODEL, SD);
    attn_kernel<<<dim3(16, 12), 256, 0, stream>>>(QKV, QKV + SD, QKV + 2 * SD,
                                                  maskp, T1);
    gemm_kernel<0><<<dim3(6, 32, 1), 256, 0, stream>>>(
        T1, aow + (long)l * DMODEL * DMODEL, aob + (long)l * DMODEL, T3, DMODEL,
        DMODEL, 0, 0, 0);
    resln_kernel<<<S_LEN, 256, 0, stream>>>(X, T3, aln_s + (long)l * DMODEL,
                                            aln_b + (long)l * DMODEL);
    gemm_kernel<1><<<dim3(24, 32, 1), 256, 0, stream>>>(
        X, w1 + (long)l * DMODEL * FFDIM, b1 + (long)l * FFDIM, T2, FFDIM,
        DMODEL, 0, 0, 0);
    gemm_kernel<0><<<dim3(6, 32, 1), 256, 0, stream>>>(
        T2, w2 + (long)l * FFDIM * DMODEL, b2 + (long)l * DMODEL, T3, DMODEL,
        FFDIM, 0, 0, 0);
    resln_kernel<<<S_LEN, 256, 0, stream>>>(X, T3, fln_s + (long)l * DMODEL,
                                            fln_b + (long)l * DMODEL);
  }

  gemm_kernel<0><<<dim3(4, 32, 1), 256, 0, stream>>>(X, c1w, c1b, H1, 512,
                                                     DMODEL, 0, 0, 0);
  gemm_kernel<0><<<dim3(4, 32, 1), 256, 0, stream>>>(H1, c2w, c2b, H2, 512, 512,
                                                     0, 0, 0);
  gemm_kernel<0><<<dim3(4, 32, 1), 256, 0, stream>>>(H2, c3w, c3b, H3, 512, 512,
                                                     0, 0, 0);
  cls_final_kernel<<<S_LEN / 4, 256, 0, stream>>>(H3, c4w, c4b, (float*)d_out);
}

// Round 2
// 3868.730 us; speedup vs baseline: 1.2695x; 1.2695x over previous
//
#include <hip/hip_runtime.h>
#include <cmath>

#define S_LEN 4096
#define DMODEL 768
#define NHEAD 12
#define DHEAD 64
#define FFDIM 3072
#define NLAYER 12
#define WINR 256

typedef float f32x4 __attribute__((ext_vector_type(4)));
typedef short s8v __attribute__((ext_vector_type(8)));
typedef __bf16 b8v __attribute__((ext_vector_type(8)));

__device__ __forceinline__ short f2b(float f) {
  unsigned u = __builtin_bit_cast(unsigned, f);
  unsigned r = (u + 0x7fffu + ((u >> 16) & 1u)) >> 16;
  return (short)r;
}
__device__ __forceinline__ float b2f(short s) {
  unsigned u = ((unsigned)(unsigned short)s) << 16;
  return __builtin_bit_cast(float, u);
}
__device__ __forceinline__ f32x4 mfma16(s8v a, s8v b, f32x4 c) {
  return __builtin_amdgcn_mfma_f32_16x16x32_bf16(
      __builtin_bit_cast(b8v, a), __builtin_bit_cast(b8v, b), c, 0, 0, 0);
}
__device__ __forceinline__ void gl_lds16(const short* g, short* l) {
  __builtin_amdgcn_global_load_lds(
      (const __attribute__((address_space(1))) unsigned int*)g,
      (__attribute__((address_space(3))) unsigned int*)l, 16, 0, 0);
}

// ---------------------------------------------------------------------------
// Weight transpose: src [K][N] f32 -> dst [N][K] bf16. grid=(N/64, K/64, cnt).
// ---------------------------------------------------------------------------
__global__ __launch_bounds__(256) void wtr_kernel(const float* __restrict__ src,
                                                  short* __restrict__ dst,
                                                  int K, int N) {
  __shared__ short tile[64][65];
  const long mo = (long)blockIdx.z * K * N;
  const int n0 = blockIdx.x * 64, k0 = blockIdx.y * 64;
  const int t = threadIdx.x;
  {
    int kr = t >> 2, nc = (t & 3) * 16;
    const float* p = src + mo + (long)(k0 + kr) * N + n0 + nc;
#pragma unroll
    for (int q = 0; q < 4; ++q) {
      float4 f = *(const float4*)(p + q * 4);
      tile[kr][nc + q * 4 + 0] = f2b(f.x);
      tile[kr][nc + q * 4 + 1] = f2b(f.y);
      tile[kr][nc + q * 4 + 2] = f2b(f.z);
      tile[kr][nc + q * 4 + 3] = f2b(f.w);
    }
  }
  __syncthreads();
  {
    int nr = t >> 2, cc = (t & 3) * 16;
    short* q = dst + mo + (long)(n0 + nr) * K + k0 + cc;
    s8v v0, v1;
#pragma unroll
    for (int j = 0; j < 8; ++j) v0[j] = tile[cc + j][nr];
#pragma unroll
    for (int j = 0; j < 8; ++j) v1[j] = tile[cc + 8 + j][nr];
    *(s8v*)q = v0;
    *(s8v*)(q + 8) = v1;
  }
}

// ---------------------------------------------------------------------------
// bf16 GEMM: C[4096,N] = A[4096,K] @ Bt[N,K]^T + bias.
// A,Bt bf16; bias f32. EPI: 0 none, 1 exact GELU, 2 scale Q (z==0) by 1/8.
// OUT: 0 f32, 1 bf16. grid=(N/128, 32, Z), block=256.
// m97-class structure: BK=64, global_load_lds(16B), ds_read_b128 frags.
// ---------------------------------------------------------------------------
template <int EPI, int OUT>
__global__ __launch_bounds__(256) void bgemm_kernel(
    const short* __restrict__ A, const short* __restrict__ Bt,
    const float* __restrict__ bias, void* __restrict__ Cv,
    int N, int K, long sB, long sBias, long sC) {
  __shared__ short As[128 * 64];
  __shared__ short Bs[128 * 64];
  const int t = threadIdx.x, lane = t & 63, w = t >> 6;
  const int lo = lane & 15, hi = lane >> 4;
  const int wm = (w >> 1) * 64, wn = (w & 1) * 64;
  const long bm = (long)blockIdx.y * 128;
  const int bn = blockIdx.x * 128;
  const int z = blockIdx.z;
  Bt += (long)z * sB;
  bias += (long)z * sBias;

  f32x4 acc[4][4];
#pragma unroll
  for (int i = 0; i < 4; ++i)
#pragma unroll
    for (int j = 0; j < 4; ++j) {
      f32x4 zz = {0.f, 0.f, 0.f, 0.f};
      acc[i][j] = zz;
    }

  const int l8 = lane >> 3, l7 = (lane & 7) * 8;
  const short* ga = A + (bm + w * 32 + l8) * (long)K + l7;
  const short* gb = Bt + ((long)bn + w * 32 + l8) * K + l7;
  short* laBase = As + (w * 32) * 64;
  short* lbBase = Bs + (w * 32) * 64;

  for (int k0 = 0; k0 < K; k0 += 64) {
    __syncthreads();
#pragma unroll
    for (int i = 0; i < 4; ++i) {
      gl_lds16(ga + k0 + (long)i * 8 * K, laBase + i * 8 * 64);
      gl_lds16(gb + k0 + (long)i * 8 * K, lbBase + i * 8 * 64);
    }
    __syncthreads();
#pragma unroll
    for (int kk = 0; kk < 2; ++kk) {
      s8v af[4], bf[4];
#pragma unroll
      for (int mi = 0; mi < 4; ++mi)
        af[mi] = *(const s8v*)(As + (wm + mi * 16 + lo) * 64 + kk * 32 + hi * 8);
#pragma unroll
      for (int ni = 0; ni < 4; ++ni)
        bf[ni] = *(const s8v*)(Bs + (wn + ni * 16 + lo) * 64 + kk * 32 + hi * 8);
#pragma unroll
      for (int mi = 0; mi < 4; ++mi)
#pragma unroll
        for (int ni = 0; ni < 4; ++ni)
          acc[mi][ni] = mfma16(af[mi], bf[ni], acc[mi][ni]);
    }
  }

  const float sc = (EPI == 2 && z == 0) ? 0.125f : 1.0f;
  float* Cf = (float*)Cv + (long)z * sC;
  short* Cs = (short*)Cv + (long)z * sC;
#pragma unroll
  for (int mi = 0; mi < 4; ++mi)
#pragma unroll
    for (int ni = 0; ni < 4; ++ni) {
      int col = bn + wn + ni * 16 + lo;
      float bb = bias[col];
#pragma unroll
      for (int jj = 0; jj < 4; ++jj) {
        long row = bm + wm + mi * 16 + hi * 4 + jj;
        float v = acc[mi][ni][jj] + bb;
        if (EPI == 2) v *= sc;
        if (EPI == 1) v = 0.5f * v * (1.0f + erff(v * 0.7071067811865476f));
        if (OUT == 0)
          Cf[row * N + col] = v;
        else
          Cs[row * N + col] = f2b(v);
      }
    }
}

// ---------------------------------------------------------------------------
// Banded flash attention, bf16 I/O. grid=(16 qblocks, 12 heads), block=256
// (4 waves x 64 q-rows). 64-key tiles; per-wave band skip; per-wave P buffer.
// ---------------------------------------------------------------------------
__global__ __launch_bounds__(256) void attn_kernel(
    const short* __restrict__ Qb, const short* __restrict__ Kb,
    const short* __restrict__ Vb, const int* __restrict__ maskp,
    short* __restrict__ Ob) {
  __shared__ short Ks[64 * 64];      // [key][d]
  __shared__ short VT[64 * 64];      // [d][key]
  __shared__ short Pl[4][64 * 64];   // per-wave [q][key]

  const int t = threadIdx.x, lane = t & 63, w = t >> 6;
  const int lo = lane & 15, hi = lane >> 4;
  const int nq = blockIdx.x, h = blockIdx.y;
  const int qbase = nq * 256 + w * 64;
  short* Plw = Pl[w];

  s8v aq[4][2];
#pragma unroll
  for (int mi = 0; mi < 4; ++mi)
#pragma unroll
    for (int kg = 0; kg < 2; ++kg)
      aq[mi][kg] = *(const s8v*)(Qb + (long)(qbase + mi * 16 + lo) * DMODEL +
                                 h * 64 + kg * 32 + hi * 8);

  f32x4 o[4][4];
#pragma unroll
  for (int i = 0; i < 4; ++i)
#pragma unroll
    for (int j = 0; j < 4; ++j) {
      f32x4 zz = {0.f, 0.f, 0.f, 0.f};
      o[i][j] = zz;
    }
  float rm[16], rl[16];
#pragma unroll
  for (int r = 0; r < 16; ++r) { rm[r] = -1e30f; rl[r] = 0.f; }

  const int kstart = max(0, (nq - 1) * WINR);
  const int kend = min(S_LEN, (nq + 2) * WINR);
  const int l8 = lane >> 3, l7 = (lane & 7) * 8;

  for (int kt = kstart; kt < kend; kt += 64) {
    __syncthreads();
    {  // stage K via global_load_lds (rows of 128B)
#pragma unroll
      for (int i = 0; i < 2; ++i) {
        const short* gk = Kb + (long)(kt + w * 16 + i * 8 + l8) * DMODEL +
                          h * 64 + l7;
        gl_lds16(gk, Ks + (w * 16 + i * 8) * 64);
      }
    }
    {  // stage V transposed (reg path)
      int key = t >> 2, dc = (t & 3) * 16;
      const short* pv = Vb + (long)(kt + key) * DMODEL + h * 64 + dc;
      s8v v0 = *(const s8v*)pv;
      s8v v1 = *(const s8v*)(pv + 8);
#pragma unroll
      for (int j = 0; j < 8; ++j) VT[(dc + j) * 64 + key] = v0[j];
#pragma unroll
      for (int j = 0; j < 8; ++j) VT[(dc + 8 + j) * 64 + key] = v1[j];
    }
    __syncthreads();

    const bool active = (kt + 63 >= qbase - WINR) && (kt <= qbase + 63 + WINR);
    if (active) {
      f32x4 sacc[4][4];
#pragma unroll
      for (int i = 0; i < 4; ++i)
#pragma unroll
        for (int j = 0; j < 4; ++j) {
          f32x4 zz = {0.f, 0.f, 0.f, 0.f};
          sacc[i][j] = zz;
        }
      s8v bk[4][2];
#pragma unroll
      for (int ni = 0; ni < 4; ++ni)
#pragma unroll
        for (int kg = 0; kg < 2; ++kg)
          bk[ni][kg] =
              *(const s8v*)(Ks + (ni * 16 + lo) * 64 + kg * 32 + hi * 8);
#pragma unroll
      for (int mi = 0; mi < 4; ++mi)
#pragma unroll
        for (int ni = 0; ni < 4; ++ni) {
          sacc[mi][ni] = mfma16(aq[mi][0], bk[ni][0], sacc[mi][ni]);
          sacc[mi][ni] = mfma16(aq[mi][1], bk[ni][1], sacc[mi][ni]);
        }

      int mval[4];
#pragma unroll
      for (int ni = 0; ni < 4; ++ni) mval[ni] = maskp[kt + ni * 16 + lo];

#pragma unroll
      for (int mi = 0; mi < 4; ++mi) {
#pragma unroll
        for (int jj = 0; jj < 4; ++jj) {
          const int r = mi * 4 + jj;
          const int qg = qbase + mi * 16 + hi * 4 + jj;
          float m0 = -1e30f;
#pragma unroll
          for (int ni = 0; ni < 4; ++ni) {
            int kg = kt + ni * 16 + lo;
            bool val = (kg >= qg - WINR) && (kg <= qg + WINR) && (mval[ni] != 0);
            float sv = val ? sacc[mi][ni][jj] : -1e30f;
            sacc[mi][ni][jj] = sv;
            m0 = fmaxf(m0, sv);
          }
          m0 = fmaxf(m0, __shfl_xor(m0, 1));
          m0 = fmaxf(m0, __shfl_xor(m0, 2));
          m0 = fmaxf(m0, __shfl_xor(m0, 4));
          m0 = fmaxf(m0, __shfl_xor(m0, 8));
          float mnew = fmaxf(rm[r], m0);
          float scl = __expf(rm[r] - mnew);
          rm[r] = mnew;
          float ts = 0.f;
#pragma unroll
          for (int ni = 0; ni < 4; ++ni) {
            float sv = sacc[mi][ni][jj];
            float p = (sv > -1e29f) ? __expf(sv - mnew) : 0.f;
            sacc[mi][ni][jj] = p;
            ts += p;
          }
          ts += __shfl_xor(ts, 1);
          ts += __shfl_xor(ts, 2);
          ts += __shfl_xor(ts, 4);
          ts += __shfl_xor(ts, 8);
          rl[r] = rl[r] * scl + ts;
#pragma unroll
          for (int di = 0; di < 4; ++di) o[mi][di][jj] *= scl;
        }
      }

#pragma unroll
      for (int mi = 0; mi < 4; ++mi)
#pragma unroll
        for (int jj = 0; jj < 4; ++jj)
#pragma unroll
          for (int ni = 0; ni < 4; ++ni)
            Plw[(mi * 16 + hi * 4 + jj) * 64 + ni * 16 + lo] =
                f2b(sacc[mi][ni][jj]);

      s8v ap[4][2], bv[4][2];
#pragma unroll
      for (int mi = 0; mi < 4; ++mi)
#pragma unroll
        for (int kg = 0; kg < 2; ++kg)
          ap[mi][kg] =
              *(const s8v*)(Plw + (mi * 16 + lo) * 64 + kg * 32 + hi * 8);
#pragma unroll
      for (int di = 0; di < 4; ++di)
#pragma unroll
        for (int kg = 0; kg < 2; ++kg)
          bv[di][kg] =
              *(const s8v*)(VT + (di * 16 + lo) * 64 + kg * 32 + hi * 8);
#pragma unroll
      for (int mi = 0; mi < 4; ++mi)
#pragma unroll
        for (int di = 0; di < 4; ++di) {
          o[mi][di] = mfma16(ap[mi][0], bv[di][0], o[mi][di]);
          o[mi][di] = mfma16(ap[mi][1], bv[di][1], o[mi][di]);
        }
    }
  }

#pragma unroll
  for (int mi = 0; mi < 4; ++mi)
#pragma unroll
    for (int di = 0; di < 4; ++di)
#pragma unroll
      for (int jj = 0; jj < 4; ++jj) {
        const int r = mi * 4 + jj;
        long row = qbase + mi * 16 + hi * 4 + jj;
        Ob[row * DMODEL + h * 64 + di * 16 + lo] = f2b(o[mi][di][jj] / rl[r]);
      }
}

// ---------------------------------------------------------------------------
// Embedding + LayerNorm, dual output (f32 X + bf16 Xb). grid=4096, block=256.
// ---------------------------------------------------------------------------
__global__ __launch_bounds__(256) void embed_ln_kernel(
    const int* __restrict__ tok, const float* __restrict__ wemb,
    const float* __restrict__ pemb, const float* __restrict__ gs,
    const float* __restrict__ gb, float* __restrict__ X,
    short* __restrict__ Xb) {
  __shared__ float sm1[4], sm2[4];
  const int row = blockIdx.x;
  const int tk = tok[row];
  float v[3];
  float s = 0.f, q = 0.f;
#pragma unroll
  for (int i = 0; i < 3; ++i) {
    int c = threadIdx.x + i * 256;
    float x = wemb[(long)tk * DMODEL + c] + pemb[(long)(row + 2) * DMODEL + c];
    v[i] = x;
    s += x;
    q += x * x;
  }
#pragma unroll
  for (int off = 32; off; off >>= 1) {
    s += __shfl_down(s, off);
    q += __shfl_down(q, off);
  }
  int w = threadIdx.x >> 6;
  if ((threadIdx.x & 63) == 0) { sm1[w] = s; sm2[w] = q; }
  __syncthreads();
  s = sm1[0] + sm1[1] + sm1[2] + sm1[3];
  q = sm2[0] + sm2[1] + sm2[2] + sm2[3];
  float mu = s * (1.f / DMODEL);
  float var = q * (1.f / DMODEL) - mu * mu;
  float inv = rsqrtf(var + 1e-5f);
#pragma unroll
  for (int i = 0; i < 3; ++i) {
    int c = threadIdx.x + i * 256;
    float y = (v[i] - mu) * inv * gs[c] + gb[c];
    X[(long)row * DMODEL + c] = y;
    Xb[(long)row * DMODEL + c] = f2b(y);
  }
}

// ---------------------------------------------------------------------------
// X = LayerNorm(X + T); also writes bf16 Xb. grid=4096, block=256.
// ---------------------------------------------------------------------------
__global__ __launch_bounds__(256) void resln_kernel(
    float* __restrict__ X, const float* __restrict__ T,
    const float* __restrict__ gs, const float* __restrict__ gb,
    short* __restrict__ Xb) {
  __shared__ float sm1[4], sm2[4];
  const int row = blockIdx.x;
  float v[3];
  float s = 0.f, q = 0.f;
#pragma unroll
  for (int i = 0; i < 3; ++i) {
    int c = threadIdx.x + i * 256;
    float x = X[(long)row * DMODEL + c] + T[(long)row * DMODEL + c];
    v[i] = x;
    s += x;
    q += x * x;
  }
#pragma unroll
  for (int off = 32; off; off >>= 1) {
    s += __shfl_down(s, off);
    q += __shfl_down(q, off);
  }
  int w = threadIdx.x >> 6;
  if ((threadIdx.x & 63) == 0) { sm1[w] = s; sm2[w] = q; }
  __syncthreads();
  s = sm1[0] + sm1[1] + sm1[2] + sm1[3];
  q = sm2[0] + sm2[1] + sm2[2] + sm2[3];
  float mu = s * (1.f / DMODEL);
  float var = q * (1.f / DMODEL) - mu * mu;
  float inv = rsqrtf(var + 1e-5f);
#pragma unroll
  for (int i = 0; i < 3; ++i) {
    int c = threadIdx.x + i * 256;
    float y = (v[i] - mu) * inv * gs[c] + gb[c];
    X[(long)row * DMODEL + c] = y;
    Xb[(long)row * DMODEL + c] = f2b(y);
  }
}

// ---------------------------------------------------------------------------
// out[row] = dot(H3[row,:512] (bf16), w4[:,0] (f32)) + b4[0].
// ---------------------------------------------------------------------------
__global__ __launch_bounds__(256) void cls_final_kernel(
    const short* __restrict__ Hh, const float* __restrict__ w4,
    const float* __restrict__ b4, float* __restrict__ out) {
  const int w = threadIdx.x >> 6, lane = threadIdx.x & 63;
  const int row = blockIdx.x * 4 + w;
  float s = 0.f;
#pragma unroll
  for (int j = 0; j < 8; ++j) {
    int k = lane + j * 64;
    s += b2f(Hh[(long)row * 512 + k]) * w4[k * 2];
  }
#pragma unroll
  for (int off = 32; off; off >>= 1) s += __shfl_down(s, off);
  if (lane == 0) out[row] = s + b4[0];
}

// ---------------------------------------------------------------------------
extern "C" void kernel_launch(void* const* d_in, const int* in_sizes, int n_in,
                              void* d_out, int out_size, void* d_ws,
                              size_t ws_size, hipStream_t stream) {
  const int* essay = (const int*)d_in[0];
  const float* wemb = (const float*)d_in[1];
  const float* pemb = (const float*)d_in[2];
  const float* eln_s = (const float*)d_in[3];
  const float* eln_b = (const float*)d_in[4];
  const float* qkv_w = (const float*)d_in[5];
  const float* qkv_b = (const float*)d_in[6];
  const float* aow = (const float*)d_in[7];
  const float* aob = (const float*)d_in[8];
  const float* aln_s = (const float*)d_in[9];
  const float* aln_b = (const float*)d_in[10];
  const float* w1 = (const float*)d_in[11];
  const float* b1 = (const float*)d_in[12];
  const float* w2 = (const float*)d_in[13];
  const float* b2 = (const float*)d_in[14];
  const float* fln_s = (const float*)d_in[15];
  const float* fln_b = (const float*)d_in[16];
  const float* c1w = (const float*)d_in[17];
  const float* c1b = (const float*)d_in[18];
  const float* c2w = (const float*)d_in[19];
  const float* c2b = (const float*)d_in[20];
  const float* c3w = (const float*)d_in[21];
  const float* c3b = (const float*)d_in[22];
  const float* c4w = (const float*)d_in[23];
  const float* c4b = (const float*)d_in[24];

  const long SD = (long)S_LEN * DMODEL;  // 3,145,728
  const long SF = (long)S_LEN * FFDIM;   // 12,582,912
  const long SH = (long)S_LEN * 512;     // 2,097,152
  const long DD = (long)DMODEL * DMODEL;
  const long DF = (long)DMODEL * FFDIM;

  // layout: f32 regions first, then bf16 (short) regions
  float* X = (float*)d_ws;
  float* T3 = X + SD;
  short* lwq = (short*)(T3 + SD);        // per-layer qkv^T: 3*DD
  short* lwa = lwq + 3 * DD;             // DD
  short* lw1 = lwa + DD;                 // DF
  short* lw2 = lw1 + DF;                 // DF
  short* c1T = lw2 + DF;                 // 768*512
  short* c2T = c1T + (long)DMODEL * 512; // 512*512
  short* c3T = c2T + 512L * 512;         // 512*512
  short* Xb = c3T + 512L * 512;          // SD
  short* QKVb = Xb + SD;                 // 3*SD
  short* T1b = QKVb + 3 * SD;            // SD
  short* T2b = T1b + SD;                 // SF
  short* H1 = T2b + SF;                  // SH
  short* H2 = H1 + SH;
  short* H3 = H2 + SH;
  const long needed = (char*)(H3 + SH) - (char*)d_ws;
  if (ws_size < (size_t)needed) return;

  const int* maskp = essay + S_LEN;

  embed_ln_kernel<<<S_LEN, 256, 0, stream>>>(essay, wemb, pemb, eln_s, eln_b, X,
                                             Xb);

  for (int l = 0; l < NLAYER; ++l) {
    wtr_kernel<<<dim3(12, 12, 3), 256, 0, stream>>>(qkv_w + l * 3 * DD, lwq,
                                                    DMODEL, DMODEL);
    wtr_kernel<<<dim3(12, 12, 1), 256, 0, stream>>>(aow + l * DD, lwa, DMODEL,
                                                    DMODEL);
    wtr_kernel<<<dim3(48, 12, 1), 256, 0, stream>>>(w1 + l * DF, lw1, DMODEL,
                                                    FFDIM);
    wtr_kernel<<<dim3(12, 48, 1), 256, 0, stream>>>(w2 + l * DF, lw2, FFDIM,
                                                    DMODEL);

    bgemm_kernel<2, 1><<<dim3(6, 32, 3), 256, 0, stream>>>(
        Xb, lwq, qkv_b + (long)l * 3 * DMODEL, QKVb, DMODEL, DMODEL, DD, DMODEL,
        SD);
    attn_kernel<<<dim3(16, 12), 256, 0, stream>>>(QKVb, QKVb + SD,
                                                  QKVb + 2 * SD, maskp, T1b);
    bgemm_kernel<0, 0><<<dim3(6, 32, 1), 256, 0, stream>>>(
        T1b, lwa, aob + (long)l * DMODEL, T3, DMODEL, DMODEL, 0, 0, 0);
    resln_kernel<<<S_LEN, 256, 0, stream>>>(X, T3, aln_s + (long)l * DMODEL,
                                            aln_b + (long)l * DMODEL, Xb);
    bgemm_kernel<1, 1><<<dim3(24, 32, 1), 256, 0, stream>>>(
        Xb, lw1, b1 + (long)l * FFDIM, T2b, FFDIM, DMODEL, 0, 0, 0);
    bgemm_kernel<0, 0><<<dim3(6, 32, 1), 256, 0, stream>>>(
        T2b, lw2, b2 + (long)l * DMODEL, T3, DMODEL, FFDIM, 0, 0, 0);
    resln_kernel<<<S_LEN, 256, 0, stream>>>(X, T3, fln_s + (long)l * DMODEL,
                                            fln_b + (long)l * DMODEL, Xb);
  }

  wtr_kernel<<<dim3(8, 12, 1), 256, 0, stream>>>(c1w, c1T, DMODEL, 512);
  wtr_kernel<<<dim3(8, 8, 1), 256, 0, stream>>>(c2w, c2T, 512, 512);
  wtr_kernel<<<dim3(8, 8, 1), 256, 0, stream>>>(c3w, c3T, 512, 512);

  bgemm_kernel<0, 1><<<dim3(4, 32, 1), 256, 0, stream>>>(Xb, c1T, c1b, H1, 512,
                                                         DMODEL, 0, 0, 0);
  bgemm_kernel<0, 1><<<dim3(4, 32, 1), 256, 0, stream>>>(H1, c2T, c2b, H2, 512,
                                                         512, 0, 0, 0);
  bgemm_kernel<0, 1><<<dim3(4, 32, 1), 256, 0, stream>>>(H2, c3T, c3b, H3, 512,
                                                         512, 0, 0, 0);
  cls_final_kernel<<<S_LEN / 4, 256, 0, stream>>>(H3, c4w, c4b, (float*)d_out);
}

// Round 3
// 3020.705 us; speedup vs baseline: 1.6259x; 1.2807x over previous
//
#include <hip/hip_runtime.h>
#include <cmath>

#define S_LEN 4096
#define DMODEL 768
#define NHEAD 12
#define DHEAD 64
#define FFDIM 3072
#define NLAYER 12
#define WINR 256

typedef float f32x4 __attribute__((ext_vector_type(4)));
typedef short s8v __attribute__((ext_vector_type(8)));
typedef __bf16 b8v __attribute__((ext_vector_type(8)));

__device__ __forceinline__ short f2b(float f) {
  unsigned u = __builtin_bit_cast(unsigned, f);
  unsigned r = (u + 0x7fffu + ((u >> 16) & 1u)) >> 16;
  return (short)r;
}
__device__ __forceinline__ float b2f(short s) {
  unsigned u = ((unsigned)(unsigned short)s) << 16;
  return __builtin_bit_cast(float, u);
}
__device__ __forceinline__ f32x4 mfma16(s8v a, s8v b, f32x4 c) {
  return __builtin_amdgcn_mfma_f32_16x16x32_bf16(
      __builtin_bit_cast(b8v, a), __builtin_bit_cast(b8v, b), c, 0, 0, 0);
}
__device__ __forceinline__ void gl_lds16(const short* g, short* l) {
  __builtin_amdgcn_global_load_lds(
      (const __attribute__((address_space(1))) unsigned int*)g,
      (__attribute__((address_space(3))) unsigned int*)l, 16, 0, 0);
}

// ---------------------------------------------------------------------------
// Weight transpose: src [K][N] f32 -> dst [N][K] bf16. grid=(N/64, K/64, cnt).
// ---------------------------------------------------------------------------
__global__ __launch_bounds__(256) void wtr_kernel(const float* __restrict__ src,
                                                  short* __restrict__ dst,
                                                  int K, int N) {
  __shared__ short tile[64][65];
  const long mo = (long)blockIdx.z * K * N;
  const int n0 = blockIdx.x * 64, k0 = blockIdx.y * 64;
  const int t = threadIdx.x;
  {
    int kr = t >> 2, nc = (t & 3) * 16;
    const float* p = src + mo + (long)(k0 + kr) * N + n0 + nc;
#pragma unroll
    for (int q = 0; q < 4; ++q) {
      float4 f = *(const float4*)(p + q * 4);
      tile[kr][nc + q * 4 + 0] = f2b(f.x);
      tile[kr][nc + q * 4 + 1] = f2b(f.y);
      tile[kr][nc + q * 4 + 2] = f2b(f.z);
      tile[kr][nc + q * 4 + 3] = f2b(f.w);
    }
  }
  __syncthreads();
  {
    int nr = t >> 2, cc = (t & 3) * 16;
    short* q = dst + mo + (long)(n0 + nr) * K + k0 + cc;
    s8v v0, v1;
#pragma unroll
    for (int j = 0; j < 8; ++j) v0[j] = tile[cc + j][nr];
#pragma unroll
    for (int j = 0; j < 8; ++j) v1[j] = tile[cc + 8 + j][nr];
    *(s8v*)q = v0;
    *(s8v*)(q + 8) = v1;
  }
}

// ---------------------------------------------------------------------------
// bf16 GEMM: C[4096,N] = A[4096,K] @ Bt[N,K]^T + bias.
// A,Bt bf16; bias f32. EPI: 0 none, 1 exact GELU, 2 scale Q (z==0) by 1/8.
// OUT: 0 f32, 1 bf16. grid=(N/128, 32, Z), block=256.
// ---------------------------------------------------------------------------
template <int EPI, int OUT>
__global__ __launch_bounds__(256) void bgemm_kernel(
    const short* __restrict__ A, const short* __restrict__ Bt,
    const float* __restrict__ bias, void* __restrict__ Cv,
    int N, int K, long sB, long sBias, long sC) {
  __shared__ short As[128 * 64];
  __shared__ short Bs[128 * 64];
  const int t = threadIdx.x, lane = t & 63, w = t >> 6;
  const int lo = lane & 15, hi = lane >> 4;
  const int wm = (w >> 1) * 64, wn = (w & 1) * 64;
  const long bm = (long)blockIdx.y * 128;
  const int bn = blockIdx.x * 128;
  const int z = blockIdx.z;
  Bt += (long)z * sB;
  bias += (long)z * sBias;

  f32x4 acc[4][4];
#pragma unroll
  for (int i = 0; i < 4; ++i)
#pragma unroll
    for (int j = 0; j < 4; ++j) {
      f32x4 zz = {0.f, 0.f, 0.f, 0.f};
      acc[i][j] = zz;
    }

  const int l8 = lane >> 3, l7 = (lane & 7) * 8;
  const short* ga = A + (bm + w * 32 + l8) * (long)K + l7;
  const short* gb = Bt + ((long)bn + w * 32 + l8) * K + l7;
  short* laBase = As + (w * 32) * 64;
  short* lbBase = Bs + (w * 32) * 64;

  for (int k0 = 0; k0 < K; k0 += 64) {
    __syncthreads();
#pragma unroll
    for (int i = 0; i < 4; ++i) {
      gl_lds16(ga + k0 + (long)i * 8 * K, laBase + i * 8 * 64);
      gl_lds16(gb + k0 + (long)i * 8 * K, lbBase + i * 8 * 64);
    }
    __syncthreads();
#pragma unroll
    for (int kk = 0; kk < 2; ++kk) {
      s8v af[4], bf[4];
#pragma unroll
      for (int mi = 0; mi < 4; ++mi)
        af[mi] = *(const s8v*)(As + (wm + mi * 16 + lo) * 64 + kk * 32 + hi * 8);
#pragma unroll
      for (int ni = 0; ni < 4; ++ni)
        bf[ni] = *(const s8v*)(Bs + (wn + ni * 16 + lo) * 64 + kk * 32 + hi * 8);
#pragma unroll
      for (int mi = 0; mi < 4; ++mi)
#pragma unroll
        for (int ni = 0; ni < 4; ++ni)
          acc[mi][ni] = mfma16(af[mi], bf[ni], acc[mi][ni]);
    }
  }

  const float sc = (EPI == 2 && z == 0) ? 0.125f : 1.0f;
  float* Cf = (float*)Cv + (long)z * sC;
  short* Cs = (short*)Cv + (long)z * sC;
#pragma unroll
  for (int mi = 0; mi < 4; ++mi)
#pragma unroll
    for (int ni = 0; ni < 4; ++ni) {
      int col = bn + wn + ni * 16 + lo;
      float bb = bias[col];
#pragma unroll
      for (int jj = 0; jj < 4; ++jj) {
        long row = bm + wm + mi * 16 + hi * 4 + jj;
        float v = acc[mi][ni][jj] + bb;
        if (EPI == 2) v *= sc;
        if (EPI == 1) v = 0.5f * v * (1.0f + erff(v * 0.7071067811865476f));
        if (OUT == 0)
          Cf[row * N + col] = v;
        else
          Cs[row * N + col] = f2b(v);
      }
    }
}

// ---------------------------------------------------------------------------
// Banded flash attention v3. grid=(64 qblocks, 12 heads), block=256 (4 waves
// x 16 q-rows). Shared 64-key K/V^T tiles, XOR-swizzled LDS (chunk ^= row&7,
// 16B chunks), all waves active on all tiles. Q pre-scaled by 1/8 upstream.
// ---------------------------------------------------------------------------
__global__ __launch_bounds__(256) void attn_kernel(
    const short* __restrict__ Qb, const short* __restrict__ Kb,
    const short* __restrict__ Vb, const int* __restrict__ maskp,
    short* __restrict__ Ob) {
  __shared__ short Ks[64 * 64];     // [key][d], swizzled
  __shared__ short VT[64 * 64];     // [d][key], swizzled
  __shared__ short Pl[4][16 * 64];  // per-wave [q][key], swizzled

  const int t = threadIdx.x, lane = t & 63, w = t >> 6;
  const int lo = lane & 15, hi = lane >> 4;
  const int q0 = blockIdx.x * 64, h = blockIdx.y;
  const int qw = q0 + w * 16;
  short* Plw = Pl[w];

  // Q A-fragment for the wave's 16 rows (rows = qw+lo, k = kg*32+hi*8)
  s8v aq[2];
#pragma unroll
  for (int kg = 0; kg < 2; ++kg)
    aq[kg] = *(const s8v*)(Qb + (long)(qw + lo) * DMODEL + h * 64 + kg * 32 +
                           hi * 8);

  f32x4 o[4];
#pragma unroll
  for (int i = 0; i < 4; ++i) {
    f32x4 zz = {0.f, 0.f, 0.f, 0.f};
    o[i] = zz;
  }
  float rm[4], rl[4];
#pragma unroll
  for (int r = 0; r < 4; ++r) { rm[r] = -1e30f; rl[r] = 0.f; }

  const int kstart = max(0, q0 - WINR);
  const int kend = min(S_LEN, q0 + 64 + WINR);

  // K staging constants: dest row offset krow, dest chunk kchunk; source
  // chunk is XOR-pre-swizzled so linear gl_lds dest yields swizzled layout.
  const int krow = lane >> 3;                    // 0..7
  const int ksrccol = ((lane & 7) ^ krow) * 8;   // shorts

  for (int kt = kstart; kt < kend; kt += 64) {
    __syncthreads();
    // --- stage K: wave w loads rows w*16 .. w*16+15 (2 x 8 rows) ---
#pragma unroll
    for (int i = 0; i < 2; ++i) {
      const int r0 = w * 16 + i * 8;  // wave-uniform base row
      gl_lds16(Kb + (long)(kt + r0 + krow) * DMODEL + h * 64 + ksrccol,
               Ks + r0 * 64);
    }
    // --- stage V^T: lane owns key=lane, d-range w*16..w*16+15 ---
    {
      const short* pv = Vb + (long)(kt + lane) * DMODEL + h * 64 + w * 16;
      s8v v0 = *(const s8v*)pv;
      s8v v1 = *(const s8v*)(pv + 8);
#pragma unroll
      for (int j = 0; j < 8; ++j)
        VT[(w * 16 + j) * 64 + (lane ^ (j << 3))] = v0[j];
#pragma unroll
      for (int j = 0; j < 8; ++j)
        VT[(w * 16 + 8 + j) * 64 + (lane ^ (j << 3))] = v1[j];
    }
    __syncthreads();

    // --- S = Q K^T (16 q-rows x 64 keys) ---
    f32x4 sacc[4];
#pragma unroll
    for (int i = 0; i < 4; ++i) {
      f32x4 zz = {0.f, 0.f, 0.f, 0.f};
      sacc[i] = zz;
    }
#pragma unroll
    for (int ni = 0; ni < 4; ++ni)
#pragma unroll
      for (int kg = 0; kg < 2; ++kg) {
        const int chunk = (kg * 4 + hi) ^ (lo & 7);
        s8v bk = *(const s8v*)(Ks + (ni * 16 + lo) * 64 + chunk * 8);
        sacc[ni] = mfma16(aq[kg], bk, sacc[ni]);
      }

    int mval[4];
#pragma unroll
    for (int ni = 0; ni < 4; ++ni) mval[ni] = maskp[kt + ni * 16 + lo];

    // --- online softmax (4 rows per lane: q = qw + hi*4 + jj) ---
#pragma unroll
    for (int jj = 0; jj < 4; ++jj) {
      const int qg = qw + hi * 4 + jj;
      float m0 = -1e30f;
#pragma unroll
      for (int ni = 0; ni < 4; ++ni) {
        int kg = kt + ni * 16 + lo;
        bool val = (kg >= qg - WINR) && (kg <= qg + WINR) && (mval[ni] != 0);
        float sv = val ? sacc[ni][jj] : -1e30f;
        sacc[ni][jj] = sv;
        m0 = fmaxf(m0, sv);
      }
      m0 = fmaxf(m0, __shfl_xor(m0, 1));
      m0 = fmaxf(m0, __shfl_xor(m0, 2));
      m0 = fmaxf(m0, __shfl_xor(m0, 4));
      m0 = fmaxf(m0, __shfl_xor(m0, 8));
      float mnew = fmaxf(rm[jj], m0);
      float scl = __expf(rm[jj] - mnew);
      rm[jj] = mnew;
      float ts = 0.f;
#pragma unroll
      for (int ni = 0; ni < 4; ++ni) {
        float sv = sacc[ni][jj];
        float p = (sv > -1e29f) ? __expf(sv - mnew) : 0.f;
        sacc[ni][jj] = p;
        ts += p;
      }
      ts += __shfl_xor(ts, 1);
      ts += __shfl_xor(ts, 2);
      ts += __shfl_xor(ts, 4);
      ts += __shfl_xor(ts, 8);
      rl[jj] = rl[jj] * scl + ts;
#pragma unroll
      for (int di = 0; di < 4; ++di) o[di][jj] *= scl;
    }

    // --- P -> per-wave LDS (swizzled) ---
#pragma unroll
    for (int jj = 0; jj < 4; ++jj) {
      const int qr = hi * 4 + jj;
#pragma unroll
      for (int ni = 0; ni < 4; ++ni) {
        const int chunk = (ni * 2 + (lo >> 3)) ^ (qr & 7);
        Plw[qr * 64 + chunk * 8 + (lo & 7)] = f2b(sacc[ni][jj]);
      }
    }

    // --- O += P @ V ---
    s8v ap[2];
#pragma unroll
    for (int kg = 0; kg < 2; ++kg) {
      const int chunk = (kg * 4 + hi) ^ (lo & 7);
      ap[kg] = *(const s8v*)(Plw + lo * 64 + chunk * 8);
    }
#pragma unroll
    for (int di = 0; di < 4; ++di)
#pragma unroll
      for (int kg = 0; kg < 2; ++kg) {
        const int chunk = (kg * 4 + hi) ^ (lo & 7);
        s8v bv = *(const s8v*)(VT + (di * 16 + lo) * 64 + chunk * 8);
        o[di] = mfma16(ap[kg], bv, o[di]);
      }
  }

  // --- write normalized output (bf16) ---
#pragma unroll
  for (int di = 0; di < 4; ++di)
#pragma unroll
    for (int jj = 0; jj < 4; ++jj) {
      long row = qw + hi * 4 + jj;
      Ob[row * DMODEL + h * 64 + di * 16 + lo] = f2b(o[di][jj] / rl[jj]);
    }
}

// ---------------------------------------------------------------------------
// Embedding + LayerNorm, dual output (f32 X + bf16 Xb). grid=4096, block=256.
// ---------------------------------------------------------------------------
__global__ __launch_bounds__(256) void embed_ln_kernel(
    const int* __restrict__ tok, const float* __restrict__ wemb,
    const float* __restrict__ pemb, const float* __restrict__ gs,
    const float* __restrict__ gb, float* __restrict__ X,
    short* __restrict__ Xb) {
  __shared__ float sm1[4], sm2[4];
  const int row = blockIdx.x;
  const int tk = tok[row];
  float v[3];
  float s = 0.f, q = 0.f;
#pragma unroll
  for (int i = 0; i < 3; ++i) {
    int c = threadIdx.x + i * 256;
    float x = wemb[(long)tk * DMODEL + c] + pemb[(long)(row + 2) * DMODEL + c];
    v[i] = x;
    s += x;
    q += x * x;
  }
#pragma unroll
  for (int off = 32; off; off >>= 1) {
    s += __shfl_down(s, off);
    q += __shfl_down(q, off);
  }
  int w = threadIdx.x >> 6;
  if ((threadIdx.x & 63) == 0) { sm1[w] = s; sm2[w] = q; }
  __syncthreads();
  s = sm1[0] + sm1[1] + sm1[2] + sm1[3];
  q = sm2[0] + sm2[1] + sm2[2] + sm2[3];
  float mu = s * (1.f / DMODEL);
  float var = q * (1.f / DMODEL) - mu * mu;
  float inv = rsqrtf(var + 1e-5f);
#pragma unroll
  for (int i = 0; i < 3; ++i) {
    int c = threadIdx.x + i * 256;
    float y = (v[i] - mu) * inv * gs[c] + gb[c];
    X[(long)row * DMODEL + c] = y;
    Xb[(long)row * DMODEL + c] = f2b(y);
  }
}

// ---------------------------------------------------------------------------
// X = LayerNorm(X + T); also writes bf16 Xb. grid=4096, block=256.
// ---------------------------------------------------------------------------
__global__ __launch_bounds__(256) void resln_kernel(
    float* __restrict__ X, const float* __restrict__ T,
    const float* __restrict__ gs, const float* __restrict__ gb,
    short* __restrict__ Xb) {
  __shared__ float sm1[4], sm2[4];
  const int row = blockIdx.x;
  float v[3];
  float s = 0.f, q = 0.f;
#pragma unroll
  for (int i = 0; i < 3; ++i) {
    int c = threadIdx.x + i * 256;
    float x = X[(long)row * DMODEL + c] + T[(long)row * DMODEL + c];
    v[i] = x;
    s += x;
    q += x * x;
  }
#pragma unroll
  for (int off = 32; off; off >>= 1) {
    s += __shfl_down(s, off);
    q += __shfl_down(q, off);
  }
  int w = threadIdx.x >> 6;
  if ((threadIdx.x & 63) == 0) { sm1[w] = s; sm2[w] = q; }
  __syncthreads();
  s = sm1[0] + sm1[1] + sm1[2] + sm1[3];
  q = sm2[0] + sm2[1] + sm2[2] + sm2[3];
  float mu = s * (1.f / DMODEL);
  float var = q * (1.f / DMODEL) - mu * mu;
  float inv = rsqrtf(var + 1e-5f);
#pragma unroll
  for (int i = 0; i < 3; ++i) {
    int c = threadIdx.x + i * 256;
    float y = (v[i] - mu) * inv * gs[c] + gb[c];
    X[(long)row * DMODEL + c] = y;
    Xb[(long)row * DMODEL + c] = f2b(y);
  }
}

// ---------------------------------------------------------------------------
// out[row] = dot(H3[row,:512] (bf16), w4[:,0] (f32)) + b4[0].
// ---------------------------------------------------------------------------
__global__ __launch_bounds__(256) void cls_final_kernel(
    const short* __restrict__ Hh, const float* __restrict__ w4,
    const float* __restrict__ b4, float* __restrict__ out) {
  const int w = threadIdx.x >> 6, lane = threadIdx.x & 63;
  const int row = blockIdx.x * 4 + w;
  float s = 0.f;
#pragma unroll
  for (int j = 0; j < 8; ++j) {
    int k = lane + j * 64;
    s += b2f(Hh[(long)row * 512 + k]) * w4[k * 2];
  }
#pragma unroll
  for (int off = 32; off; off >>= 1) s += __shfl_down(s, off);
  if (lane == 0) out[row] = s + b4[0];
}

// ---------------------------------------------------------------------------
extern "C" void kernel_launch(void* const* d_in, const int* in_sizes, int n_in,
                              void* d_out, int out_size, void* d_ws,
                              size_t ws_size, hipStream_t stream) {
  const int* essay = (const int*)d_in[0];
  const float* wemb = (const float*)d_in[1];
  const float* pemb = (const float*)d_in[2];
  const float* eln_s = (const float*)d_in[3];
  const float* eln_b = (const float*)d_in[4];
  const float* qkv_w = (const float*)d_in[5];
  const float* qkv_b = (const float*)d_in[6];
  const float* aow = (const float*)d_in[7];
  const float* aob = (const float*)d_in[8];
  const float* aln_s = (const float*)d_in[9];
  const float* aln_b = (const float*)d_in[10];
  const float* w1 = (const float*)d_in[11];
  const float* b1 = (const float*)d_in[12];
  const float* w2 = (const float*)d_in[13];
  const float* b2 = (const float*)d_in[14];
  const float* fln_s = (const float*)d_in[15];
  const float* fln_b = (const float*)d_in[16];
  const float* c1w = (const float*)d_in[17];
  const float* c1b = (const float*)d_in[18];
  const float* c2w = (const float*)d_in[19];
  const float* c2b = (const float*)d_in[20];
  const float* c3w = (const float*)d_in[21];
  const float* c3b = (const float*)d_in[22];
  const float* c4w = (const float*)d_in[23];
  const float* c4b = (const float*)d_in[24];

  const long SD = (long)S_LEN * DMODEL;
  const long SF = (long)S_LEN * FFDIM;
  const long SH = (long)S_LEN * 512;
  const long DD = (long)DMODEL * DMODEL;
  const long DF = (long)DMODEL * FFDIM;

  float* X = (float*)d_ws;
  float* T3 = X + SD;
  short* lwq = (short*)(T3 + SD);
  short* lwa = lwq + 3 * DD;
  short* lw1 = lwa + DD;
  short* lw2 = lw1 + DF;
  short* c1T = lw2 + DF;
  short* c2T = c1T + (long)DMODEL * 512;
  short* c3T = c2T + 512L * 512;
  short* Xb = c3T + 512L * 512;
  short* QKVb = Xb + SD;
  short* T1b = QKVb + 3 * SD;
  short* T2b = T1b + SD;
  short* H1 = T2b + SF;
  short* H2 = H1 + SH;
  short* H3 = H2 + SH;
  const long needed = (char*)(H3 + SH) - (char*)d_ws;
  if (ws_size < (size_t)needed) return;

  const int* maskp = essay + S_LEN;

  embed_ln_kernel<<<S_LEN, 256, 0, stream>>>(essay, wemb, pemb, eln_s, eln_b, X,
                                             Xb);

  for (int l = 0; l < NLAYER; ++l) {
    wtr_kernel<<<dim3(12, 12, 3), 256, 0, stream>>>(qkv_w + l * 3 * DD, lwq,
                                                    DMODEL, DMODEL);
    wtr_kernel<<<dim3(12, 12, 1), 256, 0, stream>>>(aow + l * DD, lwa, DMODEL,
                                                    DMODEL);
    wtr_kernel<<<dim3(48, 12, 1), 256, 0, stream>>>(w1 + l * DF, lw1, DMODEL,
                                                    FFDIM);
    wtr_kernel<<<dim3(12, 48, 1), 256, 0, stream>>>(w2 + l * DF, lw2, FFDIM,
                                                    DMODEL);

    bgemm_kernel<2, 1><<<dim3(6, 32, 3), 256, 0, stream>>>(
        Xb, lwq, qkv_b + (long)l * 3 * DMODEL, QKVb, DMODEL, DMODEL, DD, DMODEL,
        SD);
    attn_kernel<<<dim3(64, 12), 256, 0, stream>>>(QKVb, QKVb + SD,
                                                  QKVb + 2 * SD, maskp, T1b);
    bgemm_kernel<0, 0><<<dim3(6, 32, 1), 256, 0, stream>>>(
        T1b, lwa, aob + (long)l * DMODEL, T3, DMODEL, DMODEL, 0, 0, 0);
    resln_kernel<<<S_LEN, 256, 0, stream>>>(X, T3, aln_s + (long)l * DMODEL,
                                            aln_b + (long)l * DMODEL, Xb);
    bgemm_kernel<1, 1><<<dim3(24, 32, 1), 256, 0, stream>>>(
        Xb, lw1, b1 + (long)l * FFDIM, T2b, FFDIM, DMODEL, 0, 0, 0);
    bgemm_kernel<0, 0><<<dim3(6, 32, 1), 256, 0, stream>>>(
        T2b, lw2, b2 + (long)l * DMODEL, T3, DMODEL, FFDIM, 0, 0, 0);
    resln_kernel<<<S_LEN, 256, 0, stream>>>(X, T3, fln_s + (long)l * DMODEL,
                                            fln_b + (long)l * DMODEL, Xb);
  }

  wtr_kernel<<<dim3(8, 12, 1), 256, 0, stream>>>(c1w, c1T, DMODEL, 512);
  wtr_kernel<<<dim3(8, 8, 1), 256, 0, stream>>>(c2w, c2T, 512, 512);
  wtr_kernel<<<dim3(8, 8, 1), 256, 0, stream>>>(c3w, c3T, 512, 512);

  bgemm_kernel<0, 1><<<dim3(4, 32, 1), 256, 0, stream>>>(Xb, c1T, c1b, H1, 512,
                                                         DMODEL, 0, 0, 0);
  bgemm_kernel<0, 1><<<dim3(4, 32, 1), 256, 0, stream>>>(H1, c2T, c2b, H2, 512,
                                                         512, 0, 0, 0);
  bgemm_kernel<0, 1><<<dim3(4, 32, 1), 256, 0, stream>>>(H2, c3T, c3b, H3, 512,
                                                         512, 0, 0, 0);
  cls_final_kernel<<<S_LEN / 4, 256, 0, stream>>>(H3, c4w, c4b, (float*)d_out);
}

// Round 4
// 2935.480 us; speedup vs baseline: 1.6731x; 1.0290x over previous
//
#include <hip/hip_runtime.h>
#include <cmath>

#define S_LEN 4096
#define DMODEL 768
#define NHEAD 12
#define DHEAD 64
#define FFDIM 3072
#define NLAYER 12
#define WINR 256

typedef float f32x4 __attribute__((ext_vector_type(4)));
typedef short s8v __attribute__((ext_vector_type(8)));
typedef __bf16 b8v __attribute__((ext_vector_type(8)));

__device__ __forceinline__ short f2b(float f) {
  unsigned u = __builtin_bit_cast(unsigned, f);
  unsigned r = (u + 0x7fffu + ((u >> 16) & 1u)) >> 16;
  return (short)r;
}
__device__ __forceinline__ float b2f(short s) {
  unsigned u = ((unsigned)(unsigned short)s) << 16;
  return __builtin_bit_cast(float, u);
}
__device__ __forceinline__ f32x4 mfma16(s8v a, s8v b, f32x4 c) {
  return __builtin_amdgcn_mfma_f32_16x16x32_bf16(
      __builtin_bit_cast(b8v, a), __builtin_bit_cast(b8v, b), c, 0, 0, 0);
}
__device__ __forceinline__ void gl_lds16(const short* g, short* l) {
  __builtin_amdgcn_global_load_lds(
      (const __attribute__((address_space(1))) unsigned int*)g,
      (__attribute__((address_space(3))) unsigned int*)l, 16, 0, 0);
}

// log2(e)/8 : folds the 1/sqrt(DH) scale AND the exp->exp2 conversion into Q
#define QSCALE 0.18033688011112042f
#define THR2 11.5415603f  // 8 * log2(e): defer-max threshold (P <= e^8)

// ---------------------------------------------------------------------------
// Generic 64x64 transpose tile body: src [K][N] f32 -> dst [N][K] bf16.
// ---------------------------------------------------------------------------
__device__ __forceinline__ void wtr_tile(const float* __restrict__ src,
                                         short* __restrict__ dst, int K, int N,
                                         int k0, int n0, int t,
                                         short (*tile)[65]) {
  {
    int kr = t >> 2, nc = (t & 3) * 16;
    const float* p = src + (long)(k0 + kr) * N + n0 + nc;
#pragma unroll
    for (int q = 0; q < 4; ++q) {
      float4 f = *(const float4*)(p + q * 4);
      tile[kr][nc + q * 4 + 0] = f2b(f.x);
      tile[kr][nc + q * 4 + 1] = f2b(f.y);
      tile[kr][nc + q * 4 + 2] = f2b(f.z);
      tile[kr][nc + q * 4 + 3] = f2b(f.w);
    }
  }
  __syncthreads();
  {
    int nr = t >> 2, cc = (t & 3) * 16;
    short* q = dst + (long)(n0 + nr) * K + k0 + cc;
    s8v v0, v1;
#pragma unroll
    for (int j = 0; j < 8; ++j) v0[j] = tile[cc + j][nr];
#pragma unroll
    for (int j = 0; j < 8; ++j) v1[j] = tile[cc + 8 + j][nr];
    *(s8v*)q = v0;
    *(s8v*)(q + 8) = v1;
  }
}

// Standalone transpose (classifier weights). grid=(N/64, K/64).
__global__ __launch_bounds__(256) void wtr_kernel(const float* __restrict__ src,
                                                  short* __restrict__ dst,
                                                  int K, int N) {
  __shared__ short tile[64][65];
  wtr_tile(src, dst, K, N, blockIdx.y * 64, blockIdx.x * 64, threadIdx.x, tile);
}

// Fused per-layer transpose: qkv(3x768x768) + ao(768x768) + w1(768x3072) +
// w2(3072x768). grid = 1728 blocks.
__global__ __launch_bounds__(256) void wtr_layer_kernel(
    const float* __restrict__ qkv, const float* __restrict__ ao,
    const float* __restrict__ w1, const float* __restrict__ w2,
    short* __restrict__ lwq, short* __restrict__ lwa, short* __restrict__ lw1,
    short* __restrict__ lw2) {
  __shared__ short tile[64][65];
  const long DD = (long)DMODEL * DMODEL;
  int id = blockIdx.x;
  const float* src;
  short* dst;
  int K, N, nT, kT;
  if (id < 432) {
    int m = id / 144, r = id % 144;
    src = qkv + m * DD; dst = lwq + m * DD;
    K = DMODEL; N = DMODEL; nT = r % 12; kT = r / 12;
  } else if (id < 576) {
    int r = id - 432;
    src = ao; dst = lwa;
    K = DMODEL; N = DMODEL; nT = r % 12; kT = r / 12;
  } else if (id < 1152) {
    int r = id - 576;
    src = w1; dst = lw1;
    K = DMODEL; N = FFDIM; nT = r % 48; kT = r / 48;
  } else {
    int r = id - 1152;
    src = w2; dst = lw2;
    K = FFDIM; N = DMODEL; nT = r % 12; kT = r / 12;
  }
  wtr_tile(src, dst, K, N, kT * 64, nT * 64, threadIdx.x, tile);
}

// ---------------------------------------------------------------------------
// bf16 GEMM: C[4096,N] = A[4096,K] @ Bt[N,K]^T + bias.
// EPI: 0 none, 1 exact GELU, 2 scale Q (z==0) by QSCALE.
// OUT: 0 f32, 1 bf16. grid=(N/128, 32, Z), block=256.
// ---------------------------------------------------------------------------
template <int EPI, int OUT>
__global__ __launch_bounds__(256) void bgemm_kernel(
    const short* __restrict__ A, const short* __restrict__ Bt,
    const float* __restrict__ bias, void* __restrict__ Cv,
    int N, int K, long sB, long sBias, long sC) {
  __shared__ short As[128 * 64];
  __shared__ short Bs[128 * 64];
  const int t = threadIdx.x, lane = t & 63, w = t >> 6;
  const int lo = lane & 15, hi = lane >> 4;
  const int wm = (w >> 1) * 64, wn = (w & 1) * 64;
  const long bm = (long)blockIdx.y * 128;
  const int bn = blockIdx.x * 128;
  const int z = blockIdx.z;
  Bt += (long)z * sB;
  bias += (long)z * sBias;

  f32x4 acc[4][4];
#pragma unroll
  for (int i = 0; i < 4; ++i)
#pragma unroll
    for (int j = 0; j < 4; ++j) {
      f32x4 zz = {0.f, 0.f, 0.f, 0.f};
      acc[i][j] = zz;
    }

  const int l8 = lane >> 3, l7 = (lane & 7) * 8;
  const short* ga = A + (bm + w * 32 + l8) * (long)K + l7;
  const short* gb = Bt + ((long)bn + w * 32 + l8) * K + l7;
  short* laBase = As + (w * 32) * 64;
  short* lbBase = Bs + (w * 32) * 64;

  for (int k0 = 0; k0 < K; k0 += 64) {
    __syncthreads();
#pragma unroll
    for (int i = 0; i < 4; ++i) {
      gl_lds16(ga + k0 + (long)i * 8 * K, laBase + i * 8 * 64);
      gl_lds16(gb + k0 + (long)i * 8 * K, lbBase + i * 8 * 64);
    }
    __syncthreads();
#pragma unroll
    for (int kk = 0; kk < 2; ++kk) {
      s8v af[4], bf[4];
#pragma unroll
      for (int mi = 0; mi < 4; ++mi)
        af[mi] = *(const s8v*)(As + (wm + mi * 16 + lo) * 64 + kk * 32 + hi * 8);
#pragma unroll
      for (int ni = 0; ni < 4; ++ni)
        bf[ni] = *(const s8v*)(Bs + (wn + ni * 16 + lo) * 64 + kk * 32 + hi * 8);
#pragma unroll
      for (int mi = 0; mi < 4; ++mi)
#pragma unroll
        for (int ni = 0; ni < 4; ++ni)
          acc[mi][ni] = mfma16(af[mi], bf[ni], acc[mi][ni]);
    }
  }

  const float sc = (EPI == 2 && z == 0) ? QSCALE : 1.0f;
  float* Cf = (float*)Cv + (long)z * sC;
  short* Cs = (short*)Cv + (long)z * sC;
#pragma unroll
  for (int mi = 0; mi < 4; ++mi)
#pragma unroll
    for (int ni = 0; ni < 4; ++ni) {
      int col = bn + wn + ni * 16 + lo;
      float bb = bias[col];
#pragma unroll
      for (int jj = 0; jj < 4; ++jj) {
        long row = bm + wm + mi * 16 + hi * 4 + jj;
        float v = acc[mi][ni][jj] + bb;
        if (EPI == 2) v *= sc;
        if (EPI == 1) v = 0.5f * v * (1.0f + erff(v * 0.7071067811865476f));
        if (OUT == 0)
          Cf[row * N + col] = v;
        else
          Cs[row * N + col] = f2b(v);
      }
    }
}

// ---------------------------------------------------------------------------
// Banded flash attention v4. grid=(64 qblocks, 12 heads), block=256 (4 waves
// x 16 q-rows). XOR-swizzled LDS; exp2-domain softmax (Q pre-scaled by
// log2e/8); T13 defer-max; T5 setprio around MFMA clusters.
// ---------------------------------------------------------------------------
__global__ __launch_bounds__(256, 3) void attn_kernel(
    const short* __restrict__ Qb, const short* __restrict__ Kb,
    const short* __restrict__ Vb, const int* __restrict__ maskp,
    short* __restrict__ Ob) {
  __shared__ short Ks[64 * 64];     // [key][d], swizzled
  __shared__ short VT[64 * 64];     // [d][key], swizzled
  __shared__ short Pl[4][16 * 64];  // per-wave [q][key], swizzled

  const int t = threadIdx.x, lane = t & 63, w = t >> 6;
  const int lo = lane & 15, hi = lane >> 4;
  const int q0 = blockIdx.x * 64, h = blockIdx.y;
  const int qw = q0 + w * 16;
  short* Plw = Pl[w];

  s8v aq[2];
#pragma unroll
  for (int kg = 0; kg < 2; ++kg)
    aq[kg] = *(const s8v*)(Qb + (long)(qw + lo) * DMODEL + h * 64 + kg * 32 +
                           hi * 8);

  f32x4 o[4];
#pragma unroll
  for (int i = 0; i < 4; ++i) {
    f32x4 zz = {0.f, 0.f, 0.f, 0.f};
    o[i] = zz;
  }
  float rm[4], rl[4];
#pragma unroll
  for (int r = 0; r < 4; ++r) { rm[r] = -1e30f; rl[r] = 0.f; }

  const int kstart = max(0, q0 - WINR);
  const int kend = min(S_LEN, q0 + 64 + WINR);

  const int krow = lane >> 3;
  const int ksrccol = ((lane & 7) ^ krow) * 8;

  for (int kt = kstart; kt < kend; kt += 64) {
    __syncthreads();
#pragma unroll
    for (int i = 0; i < 2; ++i) {
      const int r0 = w * 16 + i * 8;
      gl_lds16(Kb + (long)(kt + r0 + krow) * DMODEL + h * 64 + ksrccol,
               Ks + r0 * 64);
    }
    {
      const short* pv = Vb + (long)(kt + lane) * DMODEL + h * 64 + w * 16;
      s8v v0 = *(const s8v*)pv;
      s8v v1 = *(const s8v*)(pv + 8);
#pragma unroll
      for (int j = 0; j < 8; ++j)
        VT[(w * 16 + j) * 64 + (lane ^ (j << 3))] = v0[j];
#pragma unroll
      for (int j = 0; j < 8; ++j)
        VT[(w * 16 + 8 + j) * 64 + (lane ^ (j << 3))] = v1[j];
    }
    __syncthreads();

    // --- S = Q K^T ---
    f32x4 sacc[4];
#pragma unroll
    for (int i = 0; i < 4; ++i) {
      f32x4 zz = {0.f, 0.f, 0.f, 0.f};
      sacc[i] = zz;
    }
    __builtin_amdgcn_s_setprio(1);
#pragma unroll
    for (int ni = 0; ni < 4; ++ni)
#pragma unroll
      for (int kg = 0; kg < 2; ++kg) {
        const int chunk = (kg * 4 + hi) ^ (lo & 7);
        s8v bk = *(const s8v*)(Ks + (ni * 16 + lo) * 64 + chunk * 8);
        sacc[ni] = mfma16(aq[kg], bk, sacc[ni]);
      }
    __builtin_amdgcn_s_setprio(0);

    int mval[4];
#pragma unroll
    for (int ni = 0; ni < 4; ++ni) mval[ni] = maskp[kt + ni * 16 + lo];

    // --- band/mask + per-row tile max ---
    float m0[4];
#pragma unroll
    for (int jj = 0; jj < 4; ++jj) {
      const int qg = qw + hi * 4 + jj;
      float mm = -1e30f;
#pragma unroll
      for (int ni = 0; ni < 4; ++ni) {
        int kg = kt + ni * 16 + lo;
        bool val = (kg >= qg - WINR) && (kg <= qg + WINR) && (mval[ni] != 0);
        float sv = val ? sacc[ni][jj] : -1e30f;
        sacc[ni][jj] = sv;
        mm = fmaxf(mm, sv);
      }
      mm = fmaxf(mm, __shfl_xor(mm, 1));
      mm = fmaxf(mm, __shfl_xor(mm, 2));
      mm = fmaxf(mm, __shfl_xor(mm, 4));
      mm = fmaxf(mm, __shfl_xor(mm, 8));
      m0[jj] = mm;
    }

    bool skipf = true;
#pragma unroll
    for (int jj = 0; jj < 4; ++jj)
      skipf = skipf && (m0[jj] - rm[jj] <= THR2);

    if (__all(skipf)) {
      // defer-max: keep old running max, no o-rescale (P bounded by e^8)
#pragma unroll
      for (int jj = 0; jj < 4; ++jj) {
        float ts = 0.f;
#pragma unroll
        for (int ni = 0; ni < 4; ++ni) {
          float sv = sacc[ni][jj];
          float p = (sv > -1e29f) ? exp2f(sv - rm[jj]) : 0.f;
          sacc[ni][jj] = p;
          ts += p;
        }
        ts += __shfl_xor(ts, 1);
        ts += __shfl_xor(ts, 2);
        ts += __shfl_xor(ts, 4);
        ts += __shfl_xor(ts, 8);
        rl[jj] += ts;
      }
    } else {
#pragma unroll
      for (int jj = 0; jj < 4; ++jj) {
        float mnew = fmaxf(rm[jj], m0[jj]);
        float scl = exp2f(rm[jj] - mnew);
        rm[jj] = mnew;
        float ts = 0.f;
#pragma unroll
        for (int ni = 0; ni < 4; ++ni) {
          float sv = sacc[ni][jj];
          float p = (sv > -1e29f) ? exp2f(sv - mnew) : 0.f;
          sacc[ni][jj] = p;
          ts += p;
        }
        ts += __shfl_xor(ts, 1);
        ts += __shfl_xor(ts, 2);
        ts += __shfl_xor(ts, 4);
        ts += __shfl_xor(ts, 8);
        rl[jj] = rl[jj] * scl + ts;
#pragma unroll
        for (int di = 0; di < 4; ++di) o[di][jj] *= scl;
      }
    }

    // --- P -> per-wave LDS (swizzled) ---
#pragma unroll
    for (int jj = 0; jj < 4; ++jj) {
      const int qr = hi * 4 + jj;
#pragma unroll
      for (int ni = 0; ni < 4; ++ni) {
        const int chunk = (ni * 2 + (lo >> 3)) ^ (qr & 7);
        Plw[qr * 64 + chunk * 8 + (lo & 7)] = f2b(sacc[ni][jj]);
      }
    }

    // --- O += P @ V ---
    s8v ap[2];
#pragma unroll
    for (int kg = 0; kg < 2; ++kg) {
      const int chunk = (kg * 4 + hi) ^ (lo & 7);
      ap[kg] = *(const s8v*)(Plw + lo * 64 + chunk * 8);
    }
    __builtin_amdgcn_s_setprio(1);
#pragma unroll
    for (int di = 0; di < 4; ++di)
#pragma unroll
      for (int kg = 0; kg < 2; ++kg) {
        const int chunk = (kg * 4 + hi) ^ (lo & 7);
        s8v bv = *(const s8v*)(VT + (di * 16 + lo) * 64 + chunk * 8);
        o[di] = mfma16(ap[kg], bv, o[di]);
      }
    __builtin_amdgcn_s_setprio(0);
  }

#pragma unroll
  for (int di = 0; di < 4; ++di)
#pragma unroll
    for (int jj = 0; jj < 4; ++jj) {
      long row = qw + hi * 4 + jj;
      Ob[row * DMODEL + h * 64 + di * 16 + lo] = f2b(o[di][jj] / rl[jj]);
    }
}

// ---------------------------------------------------------------------------
// Embedding + LayerNorm, dual output (f32 X + bf16 Xb). grid=4096, block=256.
// ---------------------------------------------------------------------------
__global__ __launch_bounds__(256) void embed_ln_kernel(
    const int* __restrict__ tok, const float* __restrict__ wemb,
    const float* __restrict__ pemb, const float* __restrict__ gs,
    const float* __restrict__ gb, float* __restrict__ X,
    short* __restrict__ Xb) {
  __shared__ float sm1[4], sm2[4];
  const int row = blockIdx.x;
  const int tk = tok[row];
  float v[3];
  float s = 0.f, q = 0.f;
#pragma unroll
  for (int i = 0; i < 3; ++i) {
    int c = threadIdx.x + i * 256;
    float x = wemb[(long)tk * DMODEL + c] + pemb[(long)(row + 2) * DMODEL + c];
    v[i] = x;
    s += x;
    q += x * x;
  }
#pragma unroll
  for (int off = 32; off; off >>= 1) {
    s += __shfl_down(s, off);
    q += __shfl_down(q, off);
  }
  int w = threadIdx.x >> 6;
  if ((threadIdx.x & 63) == 0) { sm1[w] = s; sm2[w] = q; }
  __syncthreads();
  s = sm1[0] + sm1[1] + sm1[2] + sm1[3];
  q = sm2[0] + sm2[1] + sm2[2] + sm2[3];
  float mu = s * (1.f / DMODEL);
  float var = q * (1.f / DMODEL) - mu * mu;
  float inv = rsqrtf(var + 1e-5f);
#pragma unroll
  for (int i = 0; i < 3; ++i) {
    int c = threadIdx.x + i * 256;
    float y = (v[i] - mu) * inv * gs[c] + gb[c];
    X[(long)row * DMODEL + c] = y;
    Xb[(long)row * DMODEL + c] = f2b(y);
  }
}

// ---------------------------------------------------------------------------
// X = LayerNorm(X + Tb), Tb bf16. Writes X f32 + Xb bf16. grid=4096.
// ---------------------------------------------------------------------------
__global__ __launch_bounds__(256) void resln_kernel(
    float* __restrict__ X, const short* __restrict__ Tb,
    const float* __restrict__ gs, const float* __restrict__ gb,
    short* __restrict__ Xb) {
  __shared__ float sm1[4], sm2[4];
  const int row = blockIdx.x;
  float v[3];
  float s = 0.f, q = 0.f;
#pragma unroll
  for (int i = 0; i < 3; ++i) {
    int c = threadIdx.x + i * 256;
    float x = X[(long)row * DMODEL + c] + b2f(Tb[(long)row * DMODEL + c]);
    v[i] = x;
    s += x;
    q += x * x;
  }
#pragma unroll
  for (int off = 32; off; off >>= 1) {
    s += __shfl_down(s, off);
    q += __shfl_down(q, off);
  }
  int w = threadIdx.x >> 6;
  if ((threadIdx.x & 63) == 0) { sm1[w] = s; sm2[w] = q; }
  __syncthreads();
  s = sm1[0] + sm1[1] + sm1[2] + sm1[3];
  q = sm2[0] + sm2[1] + sm2[2] + sm2[3];
  float mu = s * (1.f / DMODEL);
  float var = q * (1.f / DMODEL) - mu * mu;
  float inv = rsqrtf(var + 1e-5f);
#pragma unroll
  for (int i = 0; i < 3; ++i) {
    int c = threadIdx.x + i * 256;
    float y = (v[i] - mu) * inv * gs[c] + gb[c];
    X[(long)row * DMODEL + c] = y;
    Xb[(long)row * DMODEL + c] = f2b(y);
  }
}

// ---------------------------------------------------------------------------
// out[row] = dot(H3[row,:512] (bf16), w4[:,0] (f32)) + b4[0].
// ---------------------------------------------------------------------------
__global__ __launch_bounds__(256) void cls_final_kernel(
    const short* __restrict__ Hh, const float* __restrict__ w4,
    const float* __restrict__ b4, float* __restrict__ out) {
  const int w = threadIdx.x >> 6, lane = threadIdx.x & 63;
  const int row = blockIdx.x * 4 + w;
  float s = 0.f;
#pragma unroll
  for (int j = 0; j < 8; ++j) {
    int k = lane + j * 64;
    s += b2f(Hh[(long)row * 512 + k]) * w4[k * 2];
  }
#pragma unroll
  for (int off = 32; off; off >>= 1) s += __shfl_down(s, off);
  if (lane == 0) out[row] = s + b4[0];
}

// ---------------------------------------------------------------------------
extern "C" void kernel_launch(void* const* d_in, const int* in_sizes, int n_in,
                              void* d_out, int out_size, void* d_ws,
                              size_t ws_size, hipStream_t stream) {
  const int* essay = (const int*)d_in[0];
  const float* wemb = (const float*)d_in[1];
  const float* pemb = (const float*)d_in[2];
  const float* eln_s = (const float*)d_in[3];
  const float* eln_b = (const float*)d_in[4];
  const float* qkv_w = (const float*)d_in[5];
  const float* qkv_b = (const float*)d_in[6];
  const float* aow = (const float*)d_in[7];
  const float* aob = (const float*)d_in[8];
  const float* aln_s = (const float*)d_in[9];
  const float* aln_b = (const float*)d_in[10];
  const float* w1 = (const float*)d_in[11];
  const float* b1 = (const float*)d_in[12];
  const float* w2 = (const float*)d_in[13];
  const float* b2 = (const float*)d_in[14];
  const float* fln_s = (const float*)d_in[15];
  const float* fln_b = (const float*)d_in[16];
  const float* c1w = (const float*)d_in[17];
  const float* c1b = (const float*)d_in[18];
  const float* c2w = (const float*)d_in[19];
  const float* c2b = (const float*)d_in[20];
  const float* c3w = (const float*)d_in[21];
  const float* c3b = (const float*)d_in[22];
  const float* c4w = (const float*)d_in[23];
  const float* c4b = (const float*)d_in[24];

  const long SD = (long)S_LEN * DMODEL;
  const long SF = (long)S_LEN * FFDIM;
  const long SH = (long)S_LEN * 512;
  const long DD = (long)DMODEL * DMODEL;
  const long DF = (long)DMODEL * FFDIM;

  float* X = (float*)d_ws;
  float* T3 = X + SD;                    // region reused as bf16 T3b
  short* T3b = (short*)T3;
  short* lwq = (short*)(T3 + SD);
  short* lwa = lwq + 3 * DD;
  short* lw1 = lwa + DD;
  short* lw2 = lw1 + DF;
  short* c1T = lw2 + DF;
  short* c2T = c1T + (long)DMODEL * 512;
  short* c3T = c2T + 512L * 512;
  short* Xb = c3T + 512L * 512;
  short* QKVb = Xb + SD;
  short* T1b = QKVb + 3 * SD;
  short* T2b = T1b + SD;
  short* H1 = T2b + SF;
  short* H2 = H1 + SH;
  short* H3 = H2 + SH;
  const long needed = (char*)(H3 + SH) - (char*)d_ws;
  if (ws_size < (size_t)needed) return;

  const int* maskp = essay + S_LEN;

  embed_ln_kernel<<<S_LEN, 256, 0, stream>>>(essay, wemb, pemb, eln_s, eln_b, X,
                                             Xb);

  for (int l = 0; l < NLAYER; ++l) {
    wtr_layer_kernel<<<1728, 256, 0, stream>>>(
        qkv_w + l * 3 * DD, aow + l * DD, w1 + l * DF, w2 + l * DF, lwq, lwa,
        lw1, lw2);

    bgemm_kernel<2, 1><<<dim3(6, 32, 3), 256, 0, stream>>>(
        Xb, lwq, qkv_b + (long)l * 3 * DMODEL, QKVb, DMODEL, DMODEL, DD, DMODEL,
        SD);
    attn_kernel<<<dim3(64, 12), 256, 0, stream>>>(QKVb, QKVb + SD,
                                                  QKVb + 2 * SD, maskp, T1b);
    bgemm_kernel<0, 1><<<dim3(6, 32, 1), 256, 0, stream>>>(
        T1b, lwa, aob + (long)l * DMODEL, T3b, DMODEL, DMODEL, 0, 0, 0);
    resln_kernel<<<S_LEN, 256, 0, stream>>>(X, T3b, aln_s + (long)l * DMODEL,
                                            aln_b + (long)l * DMODEL, Xb);
    bgemm_kernel<1, 1><<<dim3(24, 32, 1), 256, 0, stream>>>(
        Xb, lw1, b1 + (long)l * FFDIM, T2b, FFDIM, DMODEL, 0, 0, 0);
    bgemm_kernel<0, 1><<<dim3(6, 32, 1), 256, 0, stream>>>(
        T2b, lw2, b2 + (long)l * DMODEL, T3b, DMODEL, FFDIM, 0, 0, 0);
    resln_kernel<<<S_LEN, 256, 0, stream>>>(X, T3b, fln_s + (long)l * DMODEL,
                                            fln_b + (long)l * DMODEL, Xb);
  }

  wtr_kernel<<<dim3(8, 12), 256, 0, stream>>>(c1w, c1T, DMODEL, 512);
  wtr_kernel<<<dim3(8, 8), 256, 0, stream>>>(c2w, c2T, 512, 512);
  wtr_kernel<<<dim3(8, 8), 256, 0, stream>>>(c3w, c3T, 512, 512);

  bgemm_kernel<0, 1><<<dim3(4, 32, 1), 256, 0, stream>>>(Xb, c1T, c1b, H1, 512,
                                                         DMODEL, 0, 0, 0);
  bgemm_kernel<0, 1><<<dim3(4, 32, 1), 256, 0, stream>>>(H1, c2T, c2b, H2, 512,
                                                         512, 0, 0, 0);
  bgemm_kernel<0, 1><<<dim3(4, 32, 1), 256, 0, stream>>>(H2, c3T, c3b, H3, 512,
                                                         512, 0, 0, 0);
  cls_final_kernel<<<S_LEN / 4, 256, 0, stream>>>(H3, c4w, c4b, (float*)d_out);
}

// Round 5
// 2787.560 us; speedup vs baseline: 1.7619x; 1.0531x over previous
//
#include <hip/hip_runtime.h>
#include <cmath>

#define S_LEN 4096
#define DMODEL 768
#define NHEAD 12
#define DHEAD 64
#define FFDIM 3072
#define NLAYER 12
#define WINR 256

typedef float f32x4 __attribute__((ext_vector_type(4)));
typedef short s8v __attribute__((ext_vector_type(8)));
typedef __bf16 b8v __attribute__((ext_vector_type(8)));

__device__ __forceinline__ short f2b(float f) {
  unsigned u = __builtin_bit_cast(unsigned, f);
  unsigned r = (u + 0x7fffu + ((u >> 16) & 1u)) >> 16;
  return (short)r;
}
__device__ __forceinline__ float b2f(short s) {
  unsigned u = ((unsigned)(unsigned short)s) << 16;
  return __builtin_bit_cast(float, u);
}
__device__ __forceinline__ f32x4 mfma16(s8v a, s8v b, f32x4 c) {
  return __builtin_amdgcn_mfma_f32_16x16x32_bf16(
      __builtin_bit_cast(b8v, a), __builtin_bit_cast(b8v, b), c, 0, 0, 0);
}
__device__ __forceinline__ void gl_lds16(const short* g, short* l) {
  __builtin_amdgcn_global_load_lds(
      (const __attribute__((address_space(1))) unsigned int*)g,
      (__attribute__((address_space(3))) unsigned int*)l, 16, 0, 0);
}

// log2(e)/8 : folds the 1/sqrt(DH) scale AND the exp->exp2 conversion into Q
#define QSCALE 0.18033688011112042f
#define THR2 11.5415603f  // 8 * log2(e)

// ---------------------------------------------------------------------------
// Weight transpose (64x64 tile body): src [K][N] f32 -> dst [N][K] bf16.
// ---------------------------------------------------------------------------
__device__ __forceinline__ void wtr_tile(const float* __restrict__ src,
                                         short* __restrict__ dst, int K, int N,
                                         int k0, int n0, int t,
                                         short (*tile)[65]) {
  {
    int kr = t >> 2, nc = (t & 3) * 16;
    const float* p = src + (long)(k0 + kr) * N + n0 + nc;
#pragma unroll
    for (int q = 0; q < 4; ++q) {
      float4 f = *(const float4*)(p + q * 4);
      tile[kr][nc + q * 4 + 0] = f2b(f.x);
      tile[kr][nc + q * 4 + 1] = f2b(f.y);
      tile[kr][nc + q * 4 + 2] = f2b(f.z);
      tile[kr][nc + q * 4 + 3] = f2b(f.w);
    }
  }
  __syncthreads();
  {
    int nr = t >> 2, cc = (t & 3) * 16;
    short* q = dst + (long)(n0 + nr) * K + k0 + cc;
    s8v v0, v1;
#pragma unroll
    for (int j = 0; j < 8; ++j) v0[j] = tile[cc + j][nr];
#pragma unroll
    for (int j = 0; j < 8; ++j) v1[j] = tile[cc + 8 + j][nr];
    *(s8v*)q = v0;
    *(s8v*)(q + 8) = v1;
  }
}

__global__ __launch_bounds__(256) void wtr_kernel(const float* __restrict__ src,
                                                  short* __restrict__ dst,
                                                  int K, int N) {
  __shared__ short tile[64][65];
  wtr_tile(src, dst, K, N, blockIdx.y * 64, blockIdx.x * 64, threadIdx.x, tile);
}

__global__ __launch_bounds__(256) void wtr_layer_kernel(
    const float* __restrict__ qkv, const float* __restrict__ ao,
    const float* __restrict__ w1, const float* __restrict__ w2,
    short* __restrict__ lwq, short* __restrict__ lwa, short* __restrict__ lw1,
    short* __restrict__ lw2) {
  __shared__ short tile[64][65];
  const long DD = (long)DMODEL * DMODEL;
  int id = blockIdx.x;
  const float* src;
  short* dst;
  int K, N, nT, kT;
  if (id < 432) {
    int m = id / 144, r = id % 144;
    src = qkv + m * DD; dst = lwq + m * DD;
    K = DMODEL; N = DMODEL; nT = r % 12; kT = r / 12;
  } else if (id < 576) {
    int r = id - 432;
    src = ao; dst = lwa;
    K = DMODEL; N = DMODEL; nT = r % 12; kT = r / 12;
  } else if (id < 1152) {
    int r = id - 576;
    src = w1; dst = lw1;
    K = DMODEL; N = FFDIM; nT = r % 48; kT = r / 48;
  } else {
    int r = id - 1152;
    src = w2; dst = lw2;
    K = FFDIM; N = DMODEL; nT = r % 12; kT = r / 12;
  }
  wtr_tile(src, dst, K, N, kT * 64, nT * 64, threadIdx.x, tile);
}

// ---------------------------------------------------------------------------
// bf16 GEMM, 2-phase double-buffered: C[4096,N] = A[4096,K] @ Bt[N,K]^T.
// EPI: 0 none, 1 exact GELU, 2 scale (z==0) by QSCALE.
// OUT: 0 f32+bias, 1 bf16+bias, 2 f32 partial no-bias (split-K: Koff=z*Klen).
// grid=(N/128, 32, Z), block=256 (4 waves). Requires gridDim.y==32, nwg%8==0.
// ---------------------------------------------------------------------------
template <int EPI, int OUT>
__global__ __launch_bounds__(256) void bgemm_kernel(
    const short* __restrict__ A, const short* __restrict__ Bt,
    const float* __restrict__ bias, void* __restrict__ Cv,
    int N, int K, int Klen, long sB, long sBias, long sC) {
  __shared__ short As[2][128 * 64];
  __shared__ short Bs[2][128 * 64];
  const int t = threadIdx.x, lane = t & 63, w = t >> 6;
  const int lo = lane & 15, hi = lane >> 4;
  const int wm = (w >> 1) * 64, wn = (w & 1) * 64;

  // bijective XCD swizzle: y-chunks of 4 per XCD (gy==32)
  const int gx = gridDim.x;
  const int bid = blockIdx.x + gx * (blockIdx.y + 32 * blockIdx.z);
  const int xcd = bid & 7;
  const int jj_ = bid >> 3;
  const int bx = jj_ % gx;
  const int t2 = jj_ / gx;
  const int by = xcd * 4 + (t2 & 3);
  const int bz = t2 >> 2;

  const long bm = (long)by * 128;
  const int bn = bx * 128;
  Bt += (long)bz * sB;
  const long Koff = (OUT == 2) ? (long)bz * Klen : 0;

  f32x4 acc[4][4];
#pragma unroll
  for (int i = 0; i < 4; ++i)
#pragma unroll
    for (int j = 0; j < 4; ++j) {
      f32x4 zz = {0.f, 0.f, 0.f, 0.f};
      acc[i][j] = zz;
    }

  const int l8 = lane >> 3, l7 = (lane & 7) * 8;
  const short* ga = A + (bm + w * 32 + l8) * (long)K + Koff + l7;
  const short* gb = Bt + ((long)bn + w * 32 + l8) * K + Koff + l7;
  const int ldso = (w * 32) * 64;

  // prologue: stage tile 0 into buffer 0
#pragma unroll
  for (int i = 0; i < 4; ++i) {
    gl_lds16(ga + (long)i * 8 * K, As[0] + ldso + i * 8 * 64);
    gl_lds16(gb + (long)i * 8 * K, Bs[0] + ldso + i * 8 * 64);
  }
  __syncthreads();

  const int nt = Klen >> 6;
  for (int kt = 0; kt < nt; ++kt) {
    const int cur = kt & 1;
    if (kt + 1 < nt) {  // issue next-tile stage before compute (overlaps MFMA)
      const long k0 = (long)(kt + 1) * 64;
#pragma unroll
      for (int i = 0; i < 4; ++i) {
        gl_lds16(ga + k0 + (long)i * 8 * K, As[cur ^ 1] + ldso + i * 8 * 64);
        gl_lds16(gb + k0 + (long)i * 8 * K, Bs[cur ^ 1] + ldso + i * 8 * 64);
      }
    }
#pragma unroll
    for (int kk = 0; kk < 2; ++kk) {
      s8v af[4], bf[4];
#pragma unroll
      for (int mi = 0; mi < 4; ++mi)
        af[mi] =
            *(const s8v*)(As[cur] + (wm + mi * 16 + lo) * 64 + kk * 32 + hi * 8);
#pragma unroll
      for (int ni = 0; ni < 4; ++ni)
        bf[ni] =
            *(const s8v*)(Bs[cur] + (wn + ni * 16 + lo) * 64 + kk * 32 + hi * 8);
#pragma unroll
      for (int mi = 0; mi < 4; ++mi)
#pragma unroll
        for (int ni = 0; ni < 4; ++ni)
          acc[mi][ni] = mfma16(af[mi], bf[ni], acc[mi][ni]);
    }
    __syncthreads();  // drains vm+lgkm: next tile staged, reads done
  }

  const float sc = (EPI == 2 && bz == 0) ? QSCALE : 1.0f;
  float* Cf = (float*)Cv + (long)bz * sC;
  short* Cs = (short*)Cv + (long)bz * sC;
  const float* bp = bias + (long)bz * sBias;
#pragma unroll
  for (int mi = 0; mi < 4; ++mi)
#pragma unroll
    for (int ni = 0; ni < 4; ++ni) {
      int col = bn + wn + ni * 16 + lo;
      float bb = (OUT == 2) ? 0.f : bp[col];
#pragma unroll
      for (int jj = 0; jj < 4; ++jj) {
        long row = bm + wm + mi * 16 + hi * 4 + jj;
        float v = acc[mi][ni][jj] + bb;
        if (EPI == 2) v *= sc;
        if (EPI == 1) v = 0.5f * v * (1.0f + erff(v * 0.7071067811865476f));
        if (OUT == 1)
          Cs[row * N + col] = f2b(v);
        else
          Cf[row * N + col] = v;
      }
    }
}

// ---------------------------------------------------------------------------
// Banded flash attention v5: dbuf K/V + async-stage (T14), one sync per tile.
// grid=(64 qblocks, 12 heads), block=256 (4 waves x 16 q-rows). XOR-swizzled
// LDS; exp2-domain softmax; defer-max. Q pre-scaled by log2e/8 upstream.
// ---------------------------------------------------------------------------
__global__ __launch_bounds__(256) void attn_kernel(
    const short* __restrict__ Qb, const short* __restrict__ Kb,
    const short* __restrict__ Vb, const int* __restrict__ maskp,
    short* __restrict__ Ob) {
  __shared__ short Ks[2][64 * 64];  // [key][d], swizzled
  __shared__ short VT[2][64 * 64];  // [d][key], swizzled
  __shared__ short Pl[4][16 * 64];  // per-wave [q][key], swizzled

  const int t = threadIdx.x, lane = t & 63, w = t >> 6;
  const int lo = lane & 15, hi = lane >> 4;

  // XCD swizzle: 8 consecutive q-blocks per XCD -> K/V window L2-resident
  const int bid = blockIdx.x + 64 * blockIdx.y;
  const int xcd = bid & 7, jb = bid >> 3;
  const int qb = xcd * 8 + (jb & 7), h = jb >> 3;

  const int q0 = qb * 64;
  const int qw = q0 + w * 16;
  short* Plw = Pl[w];

  s8v aq[2];
#pragma unroll
  for (int kg = 0; kg < 2; ++kg)
    aq[kg] = *(const s8v*)(Qb + (long)(qw + lo) * DMODEL + h * 64 + kg * 32 +
                           hi * 8);

  f32x4 o[4];
#pragma unroll
  for (int i = 0; i < 4; ++i) {
    f32x4 zz = {0.f, 0.f, 0.f, 0.f};
    o[i] = zz;
  }
  float rm[4], rl[4];
#pragma unroll
  for (int r = 0; r < 4; ++r) { rm[r] = -1e30f; rl[r] = 0.f; }

  const int kstart = max(0, q0 - WINR);
  const int kend = min(S_LEN, q0 + 64 + WINR);
  const int nt = (kend - kstart) >> 6;

  const int krow = lane >> 3;
  const int ksrccol = ((lane & 7) ^ krow) * 8;

  // prologue: stage tile 0
  {
#pragma unroll
    for (int i = 0; i < 2; ++i) {
      const int r0 = w * 16 + i * 8;
      gl_lds16(Kb + (long)(kstart + r0 + krow) * DMODEL + h * 64 + ksrccol,
               Ks[0] + r0 * 64);
    }
    const short* pv = Vb + (long)(kstart + lane) * DMODEL + h * 64 + w * 16;
    s8v v0 = *(const s8v*)pv;
    s8v v1 = *(const s8v*)(pv + 8);
#pragma unroll
    for (int j = 0; j < 8; ++j)
      VT[0][(w * 16 + j) * 64 + (lane ^ (j << 3))] = v0[j];
#pragma unroll
    for (int j = 0; j < 8; ++j)
      VT[0][(w * 16 + 8 + j) * 64 + (lane ^ (j << 3))] = v1[j];
  }
  __syncthreads();

  for (int ti = 0; ti < nt; ++ti) {
    const int kt = kstart + ti * 64;
    const int cur = ti & 1;
    const bool pf = (ti + 1 < nt);
    s8v nv0, nv1;
    if (pf) {  // T14: issue next-tile loads early (K direct-to-LDS, V to regs)
#pragma unroll
      for (int i = 0; i < 2; ++i) {
        const int r0 = w * 16 + i * 8;
        gl_lds16(Kb + (long)(kt + 64 + r0 + krow) * DMODEL + h * 64 + ksrccol,
                 Ks[cur ^ 1] + r0 * 64);
      }
      const short* pv = Vb + (long)(kt + 64 + lane) * DMODEL + h * 64 + w * 16;
      nv0 = *(const s8v*)pv;
      nv1 = *(const s8v*)(pv + 8);
    }

    const bool active = (kt + 63 >= qw - WINR) && (kt <= qw + 15 + WINR);
    if (active) {
      f32x4 sacc[4];
#pragma unroll
      for (int i = 0; i < 4; ++i) {
        f32x4 zz = {0.f, 0.f, 0.f, 0.f};
        sacc[i] = zz;
      }
#pragma unroll
      for (int ni = 0; ni < 4; ++ni)
#pragma unroll
        for (int kg = 0; kg < 2; ++kg) {
          const int chunk = (kg * 4 + hi) ^ (lo & 7);
          s8v bk = *(const s8v*)(Ks[cur] + (ni * 16 + lo) * 64 + chunk * 8);
          sacc[ni] = mfma16(aq[kg], bk, sacc[ni]);
        }

      int mval[4];
#pragma unroll
      for (int ni = 0; ni < 4; ++ni) mval[ni] = maskp[kt + ni * 16 + lo];

      float m0[4];
#pragma unroll
      for (int jj = 0; jj < 4; ++jj) {
        const int qg = qw + hi * 4 + jj;
        float mm = -1e30f;
#pragma unroll
        for (int ni = 0; ni < 4; ++ni) {
          int kg = kt + ni * 16 + lo;
          bool val = (kg >= qg - WINR) && (kg <= qg + WINR) && (mval[ni] != 0);
          float sv = val ? sacc[ni][jj] : -1e30f;
          sacc[ni][jj] = sv;
          mm = fmaxf(mm, sv);
        }
        mm = fmaxf(mm, __shfl_xor(mm, 1));
        mm = fmaxf(mm, __shfl_xor(mm, 2));
        mm = fmaxf(mm, __shfl_xor(mm, 4));
        mm = fmaxf(mm, __shfl_xor(mm, 8));
        m0[jj] = mm;
      }

      bool skipf = true;
#pragma unroll
      for (int jj = 0; jj < 4; ++jj) skipf = skipf && (m0[jj] - rm[jj] <= THR2);

      if (__all(skipf)) {
#pragma unroll
        for (int jj = 0; jj < 4; ++jj) {
          float ts = 0.f;
#pragma unroll
          for (int ni = 0; ni < 4; ++ni) {
            float sv = sacc[ni][jj];
            float p = (sv > -1e29f) ? exp2f(sv - rm[jj]) : 0.f;
            sacc[ni][jj] = p;
            ts += p;
          }
          ts += __shfl_xor(ts, 1);
          ts += __shfl_xor(ts, 2);
          ts += __shfl_xor(ts, 4);
          ts += __shfl_xor(ts, 8);
          rl[jj] += ts;
        }
      } else {
#pragma unroll
        for (int jj = 0; jj < 4; ++jj) {
          float mnew = fmaxf(rm[jj], m0[jj]);
          float scl = exp2f(rm[jj] - mnew);
          rm[jj] = mnew;
          float ts = 0.f;
#pragma unroll
          for (int ni = 0; ni < 4; ++ni) {
            float sv = sacc[ni][jj];
            float p = (sv > -1e29f) ? exp2f(sv - mnew) : 0.f;
            sacc[ni][jj] = p;
            ts += p;
          }
          ts += __shfl_xor(ts, 1);
          ts += __shfl_xor(ts, 2);
          ts += __shfl_xor(ts, 4);
          ts += __shfl_xor(ts, 8);
          rl[jj] = rl[jj] * scl + ts;
#pragma unroll
          for (int di = 0; di < 4; ++di) o[di][jj] *= scl;
        }
      }

#pragma unroll
      for (int jj = 0; jj < 4; ++jj) {
        const int qr = hi * 4 + jj;
#pragma unroll
        for (int ni = 0; ni < 4; ++ni) {
          const int chunk = (ni * 2 + (lo >> 3)) ^ (qr & 7);
          Plw[qr * 64 + chunk * 8 + (lo & 7)] = f2b(sacc[ni][jj]);
        }
      }

      s8v ap[2];
#pragma unroll
      for (int kg = 0; kg < 2; ++kg) {
        const int chunk = (kg * 4 + hi) ^ (lo & 7);
        ap[kg] = *(const s8v*)(Plw + lo * 64 + chunk * 8);
      }
#pragma unroll
      for (int di = 0; di < 4; ++di)
#pragma unroll
        for (int kg = 0; kg < 2; ++kg) {
          const int chunk = (kg * 4 + hi) ^ (lo & 7);
          s8v bv = *(const s8v*)(VT[cur] + (di * 16 + lo) * 64 + chunk * 8);
          o[di] = mfma16(ap[kg], bv, o[di]);
        }
    }

    if (pf) {  // write-late half of the V async-stage
#pragma unroll
      for (int j = 0; j < 8; ++j)
        VT[cur ^ 1][(w * 16 + j) * 64 + (lane ^ (j << 3))] = nv0[j];
#pragma unroll
      for (int j = 0; j < 8; ++j)
        VT[cur ^ 1][(w * 16 + 8 + j) * 64 + (lane ^ (j << 3))] = nv1[j];
    }
    __syncthreads();
  }

#pragma unroll
  for (int di = 0; di < 4; ++di)
#pragma unroll
    for (int jj = 0; jj < 4; ++jj) {
      long row = qw + hi * 4 + jj;
      Ob[row * DMODEL + h * 64 + di * 16 + lo] = f2b(o[di][jj] / rl[jj]);
    }
}

// ---------------------------------------------------------------------------
// Embedding + LayerNorm, dual output (f32 X + bf16 Xb). grid=4096, block=256.
// ---------------------------------------------------------------------------
__global__ __launch_bounds__(256) void embed_ln_kernel(
    const int* __restrict__ tok, const float* __restrict__ wemb,
    const float* __restrict__ pemb, const float* __restrict__ gs,
    const float* __restrict__ gb, float* __restrict__ X,
    short* __restrict__ Xb) {
  __shared__ float sm1[4], sm2[4];
  const int row = blockIdx.x;
  const int tk = tok[row];
  float v[3];
  float s = 0.f, q = 0.f;
#pragma unroll
  for (int i = 0; i < 3; ++i) {
    int c = threadIdx.x + i * 256;
    float x = wemb[(long)tk * DMODEL + c] + pemb[(long)(row + 2) * DMODEL + c];
    v[i] = x;
    s += x;
    q += x * x;
  }
#pragma unroll
  for (int off = 32; off; off >>= 1) {
    s += __shfl_down(s, off);
    q += __shfl_down(q, off);
  }
  int w = threadIdx.x >> 6;
  if ((threadIdx.x & 63) == 0) { sm1[w] = s; sm2[w] = q; }
  __syncthreads();
  s = sm1[0] + sm1[1] + sm1[2] + sm1[3];
  q = sm2[0] + sm2[1] + sm2[2] + sm2[3];
  float mu = s * (1.f / DMODEL);
  float var = q * (1.f / DMODEL) - mu * mu;
  float inv = rsqrtf(var + 1e-5f);
#pragma unroll
  for (int i = 0; i < 3; ++i) {
    int c = threadIdx.x + i * 256;
    float y = (v[i] - mu) * inv * gs[c] + gb[c];
    X[(long)row * DMODEL + c] = y;
    Xb[(long)row * DMODEL + c] = f2b(y);
  }
}

// ---------------------------------------------------------------------------
// X = LayerNorm(X + P0 + P1 + bias); writes X f32 + Xb bf16. grid=4096.
// (P0/P1 are split-K f32 partial products of the preceding GEMM.)
// ---------------------------------------------------------------------------
__global__ __launch_bounds__(256) void resln2_kernel(
    float* __restrict__ X, const float* __restrict__ P0,
    const float* __restrict__ P1, const float* __restrict__ bias,
    const float* __restrict__ gs, const float* __restrict__ gb,
    short* __restrict__ Xb) {
  __shared__ float sm1[4], sm2[4];
  const int row = blockIdx.x;
  float v[3];
  float s = 0.f, q = 0.f;
#pragma unroll
  for (int i = 0; i < 3; ++i) {
    int c = threadIdx.x + i * 256;
    long ix = (long)row * DMODEL + c;
    float x = X[ix] + P0[ix] + P1[ix] + bias[c];
    v[i] = x;
    s += x;
    q += x * x;
  }
#pragma unroll
  for (int off = 32; off; off >>= 1) {
    s += __shfl_down(s, off);
    q += __shfl_down(q, off);
  }
  int w = threadIdx.x >> 6;
  if ((threadIdx.x & 63) == 0) { sm1[w] = s; sm2[w] = q; }
  __syncthreads();
  s = sm1[0] + sm1[1] + sm1[2] + sm1[3];
  q = sm2[0] + sm2[1] + sm2[2] + sm2[3];
  float mu = s * (1.f / DMODEL);
  float var = q * (1.f / DMODEL) - mu * mu;
  float inv = rsqrtf(var + 1e-5f);
#pragma unroll
  for (int i = 0; i < 3; ++i) {
    int c = threadIdx.x + i * 256;
    float y = (v[i] - mu) * inv * gs[c] + gb[c];
    X[(long)row * DMODEL + c] = y;
    Xb[(long)row * DMODEL + c] = f2b(y);
  }
}

// ---------------------------------------------------------------------------
// out[row] = dot(H3[row,:512] (bf16), w4[:,0] (f32)) + b4[0].
// ---------------------------------------------------------------------------
__global__ __launch_bounds__(256) void cls_final_kernel(
    const short* __restrict__ Hh, const float* __restrict__ w4,
    const float* __restrict__ b4, float* __restrict__ out) {
  const int w = threadIdx.x >> 6, lane = threadIdx.x & 63;
  const int row = blockIdx.x * 4 + w;
  float s = 0.f;
#pragma unroll
  for (int j = 0; j < 8; ++j) {
    int k = lane + j * 64;
    s += b2f(Hh[(long)row * 512 + k]) * w4[k * 2];
  }
#pragma unroll
  for (int off = 32; off; off >>= 1) s += __shfl_down(s, off);
  if (lane == 0) out[row] = s + b4[0];
}

// ---------------------------------------------------------------------------
extern "C" void kernel_launch(void* const* d_in, const int* in_sizes, int n_in,
                              void* d_out, int out_size, void* d_ws,
                              size_t ws_size, hipStream_t stream) {
  const int* essay = (const int*)d_in[0];
  const float* wemb = (const float*)d_in[1];
  const float* pemb = (const float*)d_in[2];
  const float* eln_s = (const float*)d_in[3];
  const float* eln_b = (const float*)d_in[4];
  const float* qkv_w = (const float*)d_in[5];
  const float* qkv_b = (const float*)d_in[6];
  const float* aow = (const float*)d_in[7];
  const float* aob = (const float*)d_in[8];
  const float* aln_s = (const float*)d_in[9];
  const float* aln_b = (const float*)d_in[10];
  const float* w1 = (const float*)d_in[11];
  const float* b1 = (const float*)d_in[12];
  const float* w2 = (const float*)d_in[13];
  const float* b2 = (const float*)d_in[14];
  const float* fln_s = (const float*)d_in[15];
  const float* fln_b = (const float*)d_in[16];
  const float* c1w = (const float*)d_in[17];
  const float* c1b = (const float*)d_in[18];
  const float* c2w = (const float*)d_in[19];
  const float* c2b = (const float*)d_in[20];
  const float* c3w = (const float*)d_in[21];
  const float* c3b = (const float*)d_in[22];
  const float* c4w = (const float*)d_in[23];
  const float* c4b = (const float*)d_in[24];

  const long SD = (long)S_LEN * DMODEL;
  const long SF = (long)S_LEN * FFDIM;
  const long SH = (long)S_LEN * 512;
  const long DD = (long)DMODEL * DMODEL;
  const long DF = (long)DMODEL * FFDIM;

  float* X = (float*)d_ws;
  float* P0 = X + SD;
  float* P1 = P0 + SD;
  short* lwq = (short*)(P1 + SD);
  short* lwa = lwq + 3 * DD;
  short* lw1 = lwa + DD;
  short* lw2 = lw1 + DF;
  short* c1T = lw2 + DF;
  short* c2T = c1T + (long)DMODEL * 512;
  short* c3T = c2T + 512L * 512;
  short* Xb = c3T + 512L * 512;
  short* QKVb = Xb + SD;
  short* T1b = QKVb + 3 * SD;
  short* T2b = T1b + SD;
  short* H1 = T2b + SF;
  short* H2 = H1 + SH;
  short* H3 = H2 + SH;
  const long needed = (char*)(H3 + SH) - (char*)d_ws;
  if (ws_size < (size_t)needed) return;

  const int* maskp = essay + S_LEN;

  embed_ln_kernel<<<S_LEN, 256, 0, stream>>>(essay, wemb, pemb, eln_s, eln_b, X,
                                             Xb);

  for (int l = 0; l < NLAYER; ++l) {
    wtr_layer_kernel<<<1728, 256, 0, stream>>>(
        qkv_w + l * 3 * DD, aow + l * DD, w1 + l * DF, w2 + l * DF, lwq, lwa,
        lw1, lw2);

    bgemm_kernel<2, 1><<<dim3(6, 32, 3), 256, 0, stream>>>(
        Xb, lwq, qkv_b + (long)l * 3 * DMODEL, QKVb, DMODEL, DMODEL, DMODEL, DD,
        DMODEL, SD);
    attn_kernel<<<dim3(64, 12), 256, 0, stream>>>(QKVb, QKVb + SD,
                                                  QKVb + 2 * SD, maskp, T1b);
    // attn-out projection: split-K x2 -> f32 partials P0,P1
    bgemm_kernel<0, 2><<<dim3(6, 32, 2), 256, 0, stream>>>(
        T1b, lwa, aob, P0, DMODEL, DMODEL, 384, 0, 0, SD);
    resln2_kernel<<<S_LEN, 256, 0, stream>>>(X, P0, P1, aob + (long)l * DMODEL,
                                             aln_s + (long)l * DMODEL,
                                             aln_b + (long)l * DMODEL, Xb);
    bgemm_kernel<1, 1><<<dim3(24, 32, 1), 256, 0, stream>>>(
        Xb, lw1, b1 + (long)l * FFDIM, T2b, FFDIM, DMODEL, DMODEL, 0, 0, 0);
    // FFN down-projection: split-K x2 -> f32 partials P0,P1
    bgemm_kernel<0, 2><<<dim3(6, 32, 2), 256, 0, stream>>>(
        T2b, lw2, b2, P0, DMODEL, FFDIM, 1536, 0, 0, SD);
    resln2_kernel<<<S_LEN, 256, 0, stream>>>(X, P0, P1, b2 + (long)l * DMODEL,
                                             fln_s + (long)l * DMODEL,
                                             fln_b + (long)l * DMODEL, Xb);
  }

  wtr_kernel<<<dim3(8, 12), 256, 0, stream>>>(c1w, c1T, DMODEL, 512);
  wtr_kernel<<<dim3(8, 8), 256, 0, stream>>>(c2w, c2T, 512, 512);
  wtr_kernel<<<dim3(8, 8), 256, 0, stream>>>(c3w, c3T, 512, 512);

  bgemm_kernel<0, 1><<<dim3(4, 32, 1), 256, 0, stream>>>(
      Xb, c1T, c1b, H1, 512, DMODEL, DMODEL, 0, 0, 0);
  bgemm_kernel<0, 1><<<dim3(4, 32, 1), 256, 0, stream>>>(H1, c2T, c2b, H2, 512,
                                                         512, 512, 0, 0, 0);
  bgemm_kernel<0, 1><<<dim3(4, 32, 1), 256, 0, stream>>>(H2, c3T, c3b, H3, 512,
                                                         512, 512, 0, 0, 0);
  cls_final_kernel<<<S_LEN / 4, 256, 0, stream>>>(H3, c4w, c4b, (float*)d_out);
}

// Round 6
// 2342.816 us; speedup vs baseline: 2.0964x; 1.1898x over previous
//
#include <hip/hip_runtime.h>
#include <cmath>

#define S_LEN 4096
#define DMODEL 768
#define NHEAD 12
#define DHEAD 64
#define FFDIM 3072
#define NLAYER 12
#define WINR 256

typedef float f32x4 __attribute__((ext_vector_type(4)));
typedef short s8v __attribute__((ext_vector_type(8)));
typedef __bf16 b8v __attribute__((ext_vector_type(8)));

__device__ __forceinline__ short f2b(float f) {
  unsigned u = __builtin_bit_cast(unsigned, f);
  unsigned r = (u + 0x7fffu + ((u >> 16) & 1u)) >> 16;
  return (short)r;
}
__device__ __forceinline__ float b2f(short s) {
  unsigned u = ((unsigned)(unsigned short)s) << 16;
  return __builtin_bit_cast(float, u);
}
__device__ __forceinline__ f32x4 mfma16(s8v a, s8v b, f32x4 c) {
  return __builtin_amdgcn_mfma_f32_16x16x32_bf16(
      __builtin_bit_cast(b8v, a), __builtin_bit_cast(b8v, b), c, 0, 0, 0);
}
__device__ __forceinline__ void gl_lds16(const short* g, short* l) {
  __builtin_amdgcn_global_load_lds(
      (const __attribute__((address_space(1))) unsigned int*)g,
      (__attribute__((address_space(3))) unsigned int*)l, 16, 0, 0);
}

// log2(e)/8 : folds the 1/sqrt(DH) scale AND the exp->exp2 conversion into Q
#define QSCALE 0.18033688011112042f
#define THR2 11.5415603f  // 8 * log2(e)

// ---------------------------------------------------------------------------
// Weight transpose (64x64 tile body): src [K][N] f32 -> dst [N][K] bf16.
// ---------------------------------------------------------------------------
__device__ __forceinline__ void wtr_tile(const float* __restrict__ src,
                                         short* __restrict__ dst, int K, int N,
                                         int k0, int n0, int t,
                                         short (*tile)[65]) {
  {
    int kr = t >> 2, nc = (t & 3) * 16;
    const float* p = src + (long)(k0 + kr) * N + n0 + nc;
#pragma unroll
    for (int q = 0; q < 4; ++q) {
      float4 f = *(const float4*)(p + q * 4);
      tile[kr][nc + q * 4 + 0] = f2b(f.x);
      tile[kr][nc + q * 4 + 1] = f2b(f.y);
      tile[kr][nc + q * 4 + 2] = f2b(f.z);
      tile[kr][nc + q * 4 + 3] = f2b(f.w);
    }
  }
  __syncthreads();
  {
    int nr = t >> 2, cc = (t & 3) * 16;
    short* q = dst + (long)(n0 + nr) * K + k0 + cc;
    s8v v0, v1;
#pragma unroll
    for (int j = 0; j < 8; ++j) v0[j] = tile[cc + j][nr];
#pragma unroll
    for (int j = 0; j < 8; ++j) v1[j] = tile[cc + 8 + j][nr];
    *(s8v*)q = v0;
    *(s8v*)(q + 8) = v1;
  }
}

__global__ __launch_bounds__(256) void wtr_kernel(const float* __restrict__ src,
                                                  short* __restrict__ dst,
                                                  int K, int N) {
  __shared__ short tile[64][65];
  wtr_tile(src, dst, K, N, blockIdx.y * 64, blockIdx.x * 64, threadIdx.x, tile);
}

__global__ __launch_bounds__(256) void wtr_layer_kernel(
    const float* __restrict__ qkv, const float* __restrict__ ao,
    const float* __restrict__ w1, const float* __restrict__ w2,
    short* __restrict__ lwq, short* __restrict__ lwa, short* __restrict__ lw1,
    short* __restrict__ lw2) {
  __shared__ short tile[64][65];
  const long DD = (long)DMODEL * DMODEL;
  int id = blockIdx.x;
  const float* src;
  short* dst;
  int K, N, nT, kT;
  if (id < 432) {
    int m = id / 144, r = id % 144;
    src = qkv + m * DD; dst = lwq + m * DD;
    K = DMODEL; N = DMODEL; nT = r % 12; kT = r / 12;
  } else if (id < 576) {
    int r = id - 432;
    src = ao; dst = lwa;
    K = DMODEL; N = DMODEL; nT = r % 12; kT = r / 12;
  } else if (id < 1152) {
    int r = id - 576;
    src = w1; dst = lw1;
    K = DMODEL; N = FFDIM; nT = r % 48; kT = r / 48;
  } else {
    int r = id - 1152;
    src = w2; dst = lw2;
    K = FFDIM; N = DMODEL; nT = r % 12; kT = r / 12;
  }
  wtr_tile(src, dst, K, N, kT * 64, nT * 64, threadIdx.x, tile);
}

// ---------------------------------------------------------------------------
// bf16 GEMM, 2-phase double-buffered, BK=32 (32KB LDS -> 4 blocks/CU).
// C[4096,N] = A[4096,K] @ Bt[N,K]^T. Chunk-XOR swizzled LDS (16B chunks,
// chunk ^= (row>>1)&3): pre-swizzled global source + linear gl_lds dest +
// swizzled ds_read -> b128 reads at the 8-cycle bank floor.
// EPI: 0 none, 1 exact GELU, 2 scale (z==0) by QSCALE.
// OUT: 0 f32+bias, 1 bf16+bias, 2 f32 partial no-bias (split-K: Koff=z*Klen).
// grid=(N/128, 32, Z), block=256 (4 waves). Requires gridDim.y==32, nwg%8==0.
// ---------------------------------------------------------------------------
template <int EPI, int OUT>
__global__ __launch_bounds__(256, 4) void bgemm_kernel(
    const short* __restrict__ A, const short* __restrict__ Bt,
    const float* __restrict__ bias, void* __restrict__ Cv,
    int N, int K, int Klen, long sB, long sBias, long sC) {
  __shared__ short As[2][128 * 32];
  __shared__ short Bs[2][128 * 32];
  const int t = threadIdx.x, lane = t & 63, w = t >> 6;
  const int lo = lane & 15, hi = lane >> 4;
  const int wm = (w >> 1) * 64, wn = (w & 1) * 64;

  // bijective XCD swizzle: y-chunks of 4 per XCD (gy==32)
  const int gx = gridDim.x;
  const int bid = blockIdx.x + gx * (blockIdx.y + 32 * blockIdx.z);
  const int xcd = bid & 7;
  const int jj_ = bid >> 3;
  const int bx = jj_ % gx;
  const int t2 = jj_ / gx;
  const int by = xcd * 4 + (t2 & 3);
  const int bz = t2 >> 2;

  const long bm = (long)by * 128;
  const int bn = bx * 128;
  Bt += (long)bz * sB;
  const long Koff = (OUT == 2) ? (long)bz * Klen : 0;

  f32x4 acc[4][4];
#pragma unroll
  for (int i = 0; i < 4; ++i)
#pragma unroll
    for (int j = 0; j < 4; ++j) {
      f32x4 zz = {0.f, 0.f, 0.f, 0.f};
      acc[i][j] = zz;
    }

  // staging: lane -> dest (row = rBase + lane>>2, chunk = lane&3); global
  // source chunk pre-swizzled so swizzled ds_read sees the right data.
  const int srow = lane >> 2;                       // 0..15 within 16-row strip
  const int schunk = (lane & 3) ^ ((lane >> 3) & 3);  // ^= (destRow>>1)&3
  const short* ga = A + (bm + srow) * (long)K + Koff + schunk * 8;
  const short* gb = Bt + ((long)bn + srow) * K + Koff + schunk * 8;

#define STAGE(buf, koff)                                                   \
  {                                                                        \
    _Pragma("unroll") for (int i = 0; i < 2; ++i) {                        \
      const int r0 = i * 64 + w * 16;                                      \
      gl_lds16(ga + (long)r0 * K + (koff), As[buf] + r0 * 32);             \
      gl_lds16(gb + (long)r0 * K + (koff), Bs[buf] + r0 * 32);             \
    }                                                                      \
  }

  STAGE(0, 0);
  __syncthreads();

  const int nt = Klen >> 5;
  const int rchunk = (hi ^ ((lo >> 1) & 3)) * 8;  // swizzled read chunk (shorts)
  for (int kt = 0; kt < nt; ++kt) {
    const int cur = kt & 1;
    if (kt + 1 < nt) STAGE(cur ^ 1, (kt + 1) * 32);
    s8v af[4], bf[4];
#pragma unroll
    for (int mi = 0; mi < 4; ++mi)
      af[mi] = *(const s8v*)(As[cur] + (wm + mi * 16 + lo) * 32 + rchunk);
#pragma unroll
    for (int ni = 0; ni < 4; ++ni)
      bf[ni] = *(const s8v*)(Bs[cur] + (wn + ni * 16 + lo) * 32 + rchunk);
#pragma unroll
    for (int mi = 0; mi < 4; ++mi)
#pragma unroll
      for (int ni = 0; ni < 4; ++ni)
        acc[mi][ni] = mfma16(af[mi], bf[ni], acc[mi][ni]);
    __syncthreads();  // next tile staged, current reads done
  }
#undef STAGE

  const float sc = (EPI == 2 && bz == 0) ? QSCALE : 1.0f;
  float* Cf = (float*)Cv + (long)bz * sC;
  short* Cs = (short*)Cv + (long)bz * sC;
  const float* bp = bias + (long)bz * sBias;
#pragma unroll
  for (int mi = 0; mi < 4; ++mi)
#pragma unroll
    for (int ni = 0; ni < 4; ++ni) {
      int col = bn + wn + ni * 16 + lo;
      float bb = (OUT == 2) ? 0.f : bp[col];
#pragma unroll
      for (int jj = 0; jj < 4; ++jj) {
        long row = bm + wm + mi * 16 + hi * 4 + jj;
        float v = acc[mi][ni][jj] + bb;
        if (EPI == 2) v *= sc;
        if (EPI == 1) v = 0.5f * v * (1.0f + erff(v * 0.7071067811865476f));
        if (OUT == 1)
          Cs[row * N + col] = f2b(v);
        else
          Cf[row * N + col] = v;
      }
    }
}

// ---------------------------------------------------------------------------
// Banded flash attention v5: dbuf K/V + async-stage (T14), one sync per tile.
// grid=(64 qblocks, 12 heads), block=256 (4 waves x 16 q-rows). XOR-swizzled
// LDS; exp2-domain softmax; defer-max. Q pre-scaled by log2e/8 upstream.
// ---------------------------------------------------------------------------
__global__ __launch_bounds__(256) void attn_kernel(
    const short* __restrict__ Qb, const short* __restrict__ Kb,
    const short* __restrict__ Vb, const int* __restrict__ maskp,
    short* __restrict__ Ob) {
  __shared__ short Ks[2][64 * 64];  // [key][d], swizzled
  __shared__ short VT[2][64 * 64];  // [d][key], swizzled
  __shared__ short Pl[4][16 * 64];  // per-wave [q][key], swizzled

  const int t = threadIdx.x, lane = t & 63, w = t >> 6;
  const int lo = lane & 15, hi = lane >> 4;

  // XCD swizzle: 8 consecutive q-blocks per XCD -> K/V window L2-resident
  const int bid = blockIdx.x + 64 * blockIdx.y;
  const int xcd = bid & 7, jb = bid >> 3;
  const int qb = xcd * 8 + (jb & 7), h = jb >> 3;

  const int q0 = qb * 64;
  const int qw = q0 + w * 16;
  short* Plw = Pl[w];

  s8v aq[2];
#pragma unroll
  for (int kg = 0; kg < 2; ++kg)
    aq[kg] = *(const s8v*)(Qb + (long)(qw + lo) * DMODEL + h * 64 + kg * 32 +
                           hi * 8);

  f32x4 o[4];
#pragma unroll
  for (int i = 0; i < 4; ++i) {
    f32x4 zz = {0.f, 0.f, 0.f, 0.f};
    o[i] = zz;
  }
  float rm[4], rl[4];
#pragma unroll
  for (int r = 0; r < 4; ++r) { rm[r] = -1e30f; rl[r] = 0.f; }

  const int kstart = max(0, q0 - WINR);
  const int kend = min(S_LEN, q0 + 64 + WINR);
  const int nt = (kend - kstart) >> 6;

  const int krow = lane >> 3;
  const int ksrccol = ((lane & 7) ^ krow) * 8;

  // prologue: stage tile 0
  {
#pragma unroll
    for (int i = 0; i < 2; ++i) {
      const int r0 = w * 16 + i * 8;
      gl_lds16(Kb + (long)(kstart + r0 + krow) * DMODEL + h * 64 + ksrccol,
               Ks[0] + r0 * 64);
    }
    const short* pv = Vb + (long)(kstart + lane) * DMODEL + h * 64 + w * 16;
    s8v v0 = *(const s8v*)pv;
    s8v v1 = *(const s8v*)(pv + 8);
#pragma unroll
    for (int j = 0; j < 8; ++j)
      VT[0][(w * 16 + j) * 64 + (lane ^ (j << 3))] = v0[j];
#pragma unroll
    for (int j = 0; j < 8; ++j)
      VT[0][(w * 16 + 8 + j) * 64 + (lane ^ (j << 3))] = v1[j];
  }
  __syncthreads();

  for (int ti = 0; ti < nt; ++ti) {
    const int kt = kstart + ti * 64;
    const int cur = ti & 1;
    const bool pf = (ti + 1 < nt);
    s8v nv0, nv1;
    if (pf) {  // T14: issue next-tile loads early (K direct-to-LDS, V to regs)
#pragma unroll
      for (int i = 0; i < 2; ++i) {
        const int r0 = w * 16 + i * 8;
        gl_lds16(Kb + (long)(kt + 64 + r0 + krow) * DMODEL + h * 64 + ksrccol,
                 Ks[cur ^ 1] + r0 * 64);
      }
      const short* pv = Vb + (long)(kt + 64 + lane) * DMODEL + h * 64 + w * 16;
      nv0 = *(const s8v*)pv;
      nv1 = *(const s8v*)(pv + 8);
    }

    const bool active = (kt + 63 >= qw - WINR) && (kt <= qw + 15 + WINR);
    if (active) {
      f32x4 sacc[4];
#pragma unroll
      for (int i = 0; i < 4; ++i) {
        f32x4 zz = {0.f, 0.f, 0.f, 0.f};
        sacc[i] = zz;
      }
#pragma unroll
      for (int ni = 0; ni < 4; ++ni)
#pragma unroll
        for (int kg = 0; kg < 2; ++kg) {
          const int chunk = (kg * 4 + hi) ^ (lo & 7);
          s8v bk = *(const s8v*)(Ks[cur] + (ni * 16 + lo) * 64 + chunk * 8);
          sacc[ni] = mfma16(aq[kg], bk, sacc[ni]);
        }

      int mval[4];
#pragma unroll
      for (int ni = 0; ni < 4; ++ni) mval[ni] = maskp[kt + ni * 16 + lo];

      float m0[4];
#pragma unroll
      for (int jj = 0; jj < 4; ++jj) {
        const int qg = qw + hi * 4 + jj;
        float mm = -1e30f;
#pragma unroll
        for (int ni = 0; ni < 4; ++ni) {
          int kg = kt + ni * 16 + lo;
          bool val = (kg >= qg - WINR) && (kg <= qg + WINR) && (mval[ni] != 0);
          float sv = val ? sacc[ni][jj] : -1e30f;
          sacc[ni][jj] = sv;
          mm = fmaxf(mm, sv);
        }
        mm = fmaxf(mm, __shfl_xor(mm, 1));
        mm = fmaxf(mm, __shfl_xor(mm, 2));
        mm = fmaxf(mm, __shfl_xor(mm, 4));
        mm = fmaxf(mm, __shfl_xor(mm, 8));
        m0[jj] = mm;
      }

      bool skipf = true;
#pragma unroll
      for (int jj = 0; jj < 4; ++jj) skipf = skipf && (m0[jj] - rm[jj] <= THR2);

      if (__all(skipf)) {
#pragma unroll
        for (int jj = 0; jj < 4; ++jj) {
          float ts = 0.f;
#pragma unroll
          for (int ni = 0; ni < 4; ++ni) {
            float sv = sacc[ni][jj];
            float p = (sv > -1e29f) ? exp2f(sv - rm[jj]) : 0.f;
            sacc[ni][jj] = p;
            ts += p;
          }
          ts += __shfl_xor(ts, 1);
          ts += __shfl_xor(ts, 2);
          ts += __shfl_xor(ts, 4);
          ts += __shfl_xor(ts, 8);
          rl[jj] += ts;
        }
      } else {
#pragma unroll
        for (int jj = 0; jj < 4; ++jj) {
          float mnew = fmaxf(rm[jj], m0[jj]);
          float scl = exp2f(rm[jj] - mnew);
          rm[jj] = mnew;
          float ts = 0.f;
#pragma unroll
          for (int ni = 0; ni < 4; ++ni) {
            float sv = sacc[ni][jj];
            float p = (sv > -1e29f) ? exp2f(sv - mnew) : 0.f;
            sacc[ni][jj] = p;
            ts += p;
          }
          ts += __shfl_xor(ts, 1);
          ts += __shfl_xor(ts, 2);
          ts += __shfl_xor(ts, 4);
          ts += __shfl_xor(ts, 8);
          rl[jj] = rl[jj] * scl + ts;
#pragma unroll
          for (int di = 0; di < 4; ++di) o[di][jj] *= scl;
        }
      }

#pragma unroll
      for (int jj = 0; jj < 4; ++jj) {
        const int qr = hi * 4 + jj;
#pragma unroll
        for (int ni = 0; ni < 4; ++ni) {
          const int chunk = (ni * 2 + (lo >> 3)) ^ (qr & 7);
          Plw[qr * 64 + chunk * 8 + (lo & 7)] = f2b(sacc[ni][jj]);
        }
      }

      s8v ap[2];
#pragma unroll
      for (int kg = 0; kg < 2; ++kg) {
        const int chunk = (kg * 4 + hi) ^ (lo & 7);
        ap[kg] = *(const s8v*)(Plw + lo * 64 + chunk * 8);
      }
#pragma unroll
      for (int di = 0; di < 4; ++di)
#pragma unroll
        for (int kg = 0; kg < 2; ++kg) {
          const int chunk = (kg * 4 + hi) ^ (lo & 7);
          s8v bv = *(const s8v*)(VT[cur] + (di * 16 + lo) * 64 + chunk * 8);
          o[di] = mfma16(ap[kg], bv, o[di]);
        }
    }

    if (pf) {  // write-late half of the V async-stage
#pragma unroll
      for (int j = 0; j < 8; ++j)
        VT[cur ^ 1][(w * 16 + j) * 64 + (lane ^ (j << 3))] = nv0[j];
#pragma unroll
      for (int j = 0; j < 8; ++j)
        VT[cur ^ 1][(w * 16 + 8 + j) * 64 + (lane ^ (j << 3))] = nv1[j];
    }
    __syncthreads();
  }

#pragma unroll
  for (int di = 0; di < 4; ++di)
#pragma unroll
    for (int jj = 0; jj < 4; ++jj) {
      long row = qw + hi * 4 + jj;
      Ob[row * DMODEL + h * 64 + di * 16 + lo] = f2b(o[di][jj] / rl[jj]);
    }
}

// ---------------------------------------------------------------------------
// Embedding + LayerNorm, dual output (f32 X + bf16 Xb). grid=4096, block=256.
// ---------------------------------------------------------------------------
__global__ __launch_bounds__(256) void embed_ln_kernel(
    const int* __restrict__ tok, const float* __restrict__ wemb,
    const float* __restrict__ pemb, const float* __restrict__ gs,
    const float* __restrict__ gb, float* __restrict__ X,
    short* __restrict__ Xb) {
  __shared__ float sm1[4], sm2[4];
  const int row = blockIdx.x;
  const int tk = tok[row];
  float v[3];
  float s = 0.f, q = 0.f;
#pragma unroll
  for (int i = 0; i < 3; ++i) {
    int c = threadIdx.x + i * 256;
    float x = wemb[(long)tk * DMODEL + c] + pemb[(long)(row + 2) * DMODEL + c];
    v[i] = x;
    s += x;
    q += x * x;
  }
#pragma unroll
  for (int off = 32; off; off >>= 1) {
    s += __shfl_down(s, off);
    q += __shfl_down(q, off);
  }
  int w = threadIdx.x >> 6;
  if ((threadIdx.x & 63) == 0) { sm1[w] = s; sm2[w] = q; }
  __syncthreads();
  s = sm1[0] + sm1[1] + sm1[2] + sm1[3];
  q = sm2[0] + sm2[1] + sm2[2] + sm2[3];
  float mu = s * (1.f / DMODEL);
  float var = q * (1.f / DMODEL) - mu * mu;
  float inv = rsqrtf(var + 1e-5f);
#pragma unroll
  for (int i = 0; i < 3; ++i) {
    int c = threadIdx.x + i * 256;
    float y = (v[i] - mu) * inv * gs[c] + gb[c];
    X[(long)row * DMODEL + c] = y;
    Xb[(long)row * DMODEL + c] = f2b(y);
  }
}

// ---------------------------------------------------------------------------
// X = LayerNorm(X + P0 + P1 + bias); writes X f32 + Xb bf16. grid=4096.
// (P0/P1 are split-K f32 partial products of the preceding GEMM.)
// ---------------------------------------------------------------------------
__global__ __launch_bounds__(256) void resln2_kernel(
    float* __restrict__ X, const float* __restrict__ P0,
    const float* __restrict__ P1, const float* __restrict__ bias,
    const float* __restrict__ gs, const float* __restrict__ gb,
    short* __restrict__ Xb) {
  __shared__ float sm1[4], sm2[4];
  const int row = blockIdx.x;
  float v[3];
  float s = 0.f, q = 0.f;
#pragma unroll
  for (int i = 0; i < 3; ++i) {
    int c = threadIdx.x + i * 256;
    long ix = (long)row * DMODEL + c;
    float x = X[ix] + P0[ix] + P1[ix] + bias[c];
    v[i] = x;
    s += x;
    q += x * x;
  }
#pragma unroll
  for (int off = 32; off; off >>= 1) {
    s += __shfl_down(s, off);
    q += __shfl_down(q, off);
  }
  int w = threadIdx.x >> 6;
  if ((threadIdx.x & 63) == 0) { sm1[w] = s; sm2[w] = q; }
  __syncthreads();
  s = sm1[0] + sm1[1] + sm1[2] + sm1[3];
  q = sm2[0] + sm2[1] + sm2[2] + sm2[3];
  float mu = s * (1.f / DMODEL);
  float var = q * (1.f / DMODEL) - mu * mu;
  float inv = rsqrtf(var + 1e-5f);
#pragma unroll
  for (int i = 0; i < 3; ++i) {
    int c = threadIdx.x + i * 256;
    float y = (v[i] - mu) * inv * gs[c] + gb[c];
    X[(long)row * DMODEL + c] = y;
    Xb[(long)row * DMODEL + c] = f2b(y);
  }
}

// ---------------------------------------------------------------------------
// out[row] = dot(H3[row,:512] (bf16), w4[:,0] (f32)) + b4[0].
// ---------------------------------------------------------------------------
__global__ __launch_bounds__(256) void cls_final_kernel(
    const short* __restrict__ Hh, const float* __restrict__ w4,
    const float* __restrict__ b4, float* __restrict__ out) {
  const int w = threadIdx.x >> 6, lane = threadIdx.x & 63;
  const int row = blockIdx.x * 4 + w;
  float s = 0.f;
#pragma unroll
  for (int j = 0; j < 8; ++j) {
    int k = lane + j * 64;
    s += b2f(Hh[(long)row * 512 + k]) * w4[k * 2];
  }
#pragma unroll
  for (int off = 32; off; off >>= 1) s += __shfl_down(s, off);
  if (lane == 0) out[row] = s + b4[0];
}

// ---------------------------------------------------------------------------
extern "C" void kernel_launch(void* const* d_in, const int* in_sizes, int n_in,
                              void* d_out, int out_size, void* d_ws,
                              size_t ws_size, hipStream_t stream) {
  const int* essay = (const int*)d_in[0];
  const float* wemb = (const float*)d_in[1];
  const float* pemb = (const float*)d_in[2];
  const float* eln_s = (const float*)d_in[3];
  const float* eln_b = (const float*)d_in[4];
  const float* qkv_w = (const float*)d_in[5];
  const float* qkv_b = (const float*)d_in[6];
  const float* aow = (const float*)d_in[7];
  const float* aob = (const float*)d_in[8];
  const float* aln_s = (const float*)d_in[9];
  const float* aln_b = (const float*)d_in[10];
  const float* w1 = (const float*)d_in[11];
  const float* b1 = (const float*)d_in[12];
  const float* w2 = (const float*)d_in[13];
  const float* b2 = (const float*)d_in[14];
  const float* fln_s = (const float*)d_in[15];
  const float* fln_b = (const float*)d_in[16];
  const float* c1w = (const float*)d_in[17];
  const float* c1b = (const float*)d_in[18];
  const float* c2w = (const float*)d_in[19];
  const float* c2b = (const float*)d_in[20];
  const float* c3w = (const float*)d_in[21];
  const float* c3b = (const float*)d_in[22];
  const float* c4w = (const float*)d_in[23];
  const float* c4b = (const float*)d_in[24];

  const long SD = (long)S_LEN * DMODEL;
  const long SF = (long)S_LEN * FFDIM;
  const long SH = (long)S_LEN * 512;
  const long DD = (long)DMODEL * DMODEL;
  const long DF = (long)DMODEL * FFDIM;

  float* X = (float*)d_ws;
  float* P0 = X + SD;
  float* P1 = P0 + SD;
  short* lwq = (short*)(P1 + SD);
  short* lwa = lwq + 3 * DD;
  short* lw1 = lwa + DD;
  short* lw2 = lw1 + DF;
  short* c1T = lw2 + DF;
  short* c2T = c1T + (long)DMODEL * 512;
  short* c3T = c2T + 512L * 512;
  short* Xb = c3T + 512L * 512;
  short* QKVb = Xb + SD;
  short* T1b = QKVb + 3 * SD;
  short* T2b = T1b + SD;
  short* H1 = T2b + SF;
  short* H2 = H1 + SH;
  short* H3 = H2 + SH;
  const long needed = (char*)(H3 + SH) - (char*)d_ws;
  if (ws_size < (size_t)needed) return;

  const int* maskp = essay + S_LEN;

  embed_ln_kernel<<<S_LEN, 256, 0, stream>>>(essay, wemb, pemb, eln_s, eln_b, X,
                                             Xb);

  for (int l = 0; l < NLAYER; ++l) {
    wtr_layer_kernel<<<1728, 256, 0, stream>>>(
        qkv_w + l * 3 * DD, aow + l * DD, w1 + l * DF, w2 + l * DF, lwq, lwa,
        lw1, lw2);

    bgemm_kernel<2, 1><<<dim3(6, 32, 3), 256, 0, stream>>>(
        Xb, lwq, qkv_b + (long)l * 3 * DMODEL, QKVb, DMODEL, DMODEL, DMODEL, DD,
        DMODEL, SD);
    attn_kernel<<<dim3(64, 12), 256, 0, stream>>>(QKVb, QKVb + SD,
                                                  QKVb + 2 * SD, maskp, T1b);
    // attn-out projection: split-K x2 -> f32 partials P0,P1
    bgemm_kernel<0, 2><<<dim3(6, 32, 2), 256, 0, stream>>>(
        T1b, lwa, aob, P0, DMODEL, DMODEL, 384, 0, 0, SD);
    resln2_kernel<<<S_LEN, 256, 0, stream>>>(X, P0, P1, aob + (long)l * DMODEL,
                                             aln_s + (long)l * DMODEL,
                                             aln_b + (long)l * DMODEL, Xb);
    bgemm_kernel<1, 1><<<dim3(24, 32, 1), 256, 0, stream>>>(
        Xb, lw1, b1 + (long)l * FFDIM, T2b, FFDIM, DMODEL, DMODEL, 0, 0, 0);
    // FFN down-projection: split-K x2 -> f32 partials P0,P1
    bgemm_kernel<0, 2><<<dim3(6, 32, 2), 256, 0, stream>>>(
        T2b, lw2, b2, P0, DMODEL, FFDIM, 1536, 0, 0, SD);
    resln2_kernel<<<S_LEN, 256, 0, stream>>>(X, P0, P1, b2 + (long)l * DMODEL,
                                             fln_s + (long)l * DMODEL,
                                             fln_b + (long)l * DMODEL, Xb);
  }

  wtr_kernel<<<dim3(8, 12), 256, 0, stream>>>(c1w, c1T, DMODEL, 512);
  wtr_kernel<<<dim3(8, 8), 256, 0, stream>>>(c2w, c2T, 512, 512);
  wtr_kernel<<<dim3(8, 8), 256, 0, stream>>>(c3w, c3T, 512, 512);

  bgemm_kernel<0, 1><<<dim3(4, 32, 1), 256, 0, stream>>>(
      Xb, c1T, c1b, H1, 512, DMODEL, DMODEL, 0, 0, 0);
  bgemm_kernel<0, 1><<<dim3(4, 32, 1), 256, 0, stream>>>(H1, c2T, c2b, H2, 512,
                                                         512, 512, 0, 0, 0);
  bgemm_kernel<0, 1><<<dim3(4, 32, 1), 256, 0, stream>>>(H2, c3T, c3b, H3, 512,
                                                         512, 512, 0, 0, 0);
  cls_final_kernel<<<S_LEN / 4, 256, 0, stream>>>(H3, c4w, c4b, (float*)d_out);
}

// Round 7
// 2246.628 us; speedup vs baseline: 2.1861x; 1.0428x over previous
//
#include <hip/hip_runtime.h>
#include <cmath>

#define S_LEN 4096
#define DMODEL 768
#define NHEAD 12
#define DHEAD 64
#define FFDIM 3072
#define NLAYER 12
#define WINR 256

typedef float f32x4 __attribute__((ext_vector_type(4)));
typedef short s8v __attribute__((ext_vector_type(8)));
typedef __bf16 b8v __attribute__((ext_vector_type(8)));

__device__ __forceinline__ short f2b(float f) {
  unsigned u = __builtin_bit_cast(unsigned, f);
  unsigned r = (u + 0x7fffu + ((u >> 16) & 1u)) >> 16;
  return (short)r;
}
__device__ __forceinline__ float b2f(short s) {
  unsigned u = ((unsigned)(unsigned short)s) << 16;
  return __builtin_bit_cast(float, u);
}
__device__ __forceinline__ f32x4 mfma16(s8v a, s8v b, f32x4 c) {
  return __builtin_amdgcn_mfma_f32_16x16x32_bf16(
      __builtin_bit_cast(b8v, a), __builtin_bit_cast(b8v, b), c, 0, 0, 0);
}
__device__ __forceinline__ void gl_lds16(const short* g, short* l) {
  __builtin_amdgcn_global_load_lds(
      (const __attribute__((address_space(1))) unsigned int*)g,
      (__attribute__((address_space(3))) unsigned int*)l, 16, 0, 0);
}

// log2(e)/8 : folds the 1/sqrt(DH) scale AND the exp->exp2 conversion into Q
#define QSCALE 0.18033688011112042f
#define THR2 11.5415603f  // 8 * log2(e)

// ---------------------------------------------------------------------------
// Weight transpose (64x64 tile body): src [K][N] f32 -> dst [N][K] bf16.
// ---------------------------------------------------------------------------
__device__ __forceinline__ void wtr_tile(const float* __restrict__ src,
                                         short* __restrict__ dst, int K, int N,
                                         int k0, int n0, int t,
                                         short (*tile)[65]) {
  {
    int kr = t >> 2, nc = (t & 3) * 16;
    const float* p = src + (long)(k0 + kr) * N + n0 + nc;
#pragma unroll
    for (int q = 0; q < 4; ++q) {
      float4 f = *(const float4*)(p + q * 4);
      tile[kr][nc + q * 4 + 0] = f2b(f.x);
      tile[kr][nc + q * 4 + 1] = f2b(f.y);
      tile[kr][nc + q * 4 + 2] = f2b(f.z);
      tile[kr][nc + q * 4 + 3] = f2b(f.w);
    }
  }
  __syncthreads();
  {
    int nr = t >> 2, cc = (t & 3) * 16;
    short* q = dst + (long)(n0 + nr) * K + k0 + cc;
    s8v v0, v1;
#pragma unroll
    for (int j = 0; j < 8; ++j) v0[j] = tile[cc + j][nr];
#pragma unroll
    for (int j = 0; j < 8; ++j) v1[j] = tile[cc + 8 + j][nr];
    *(s8v*)q = v0;
    *(s8v*)(q + 8) = v1;
  }
}

__global__ __launch_bounds__(256) void wtr_kernel(const float* __restrict__ src,
                                                  short* __restrict__ dst,
                                                  int K, int N) {
  __shared__ short tile[64][65];
  wtr_tile(src, dst, K, N, blockIdx.y * 64, blockIdx.x * 64, threadIdx.x, tile);
}

__global__ __launch_bounds__(256) void wtr_layer_kernel(
    const float* __restrict__ qkv, const float* __restrict__ ao,
    const float* __restrict__ w1, const float* __restrict__ w2,
    short* __restrict__ lwq, short* __restrict__ lwa, short* __restrict__ lw1,
    short* __restrict__ lw2) {
  __shared__ short tile[64][65];
  const long DD = (long)DMODEL * DMODEL;
  int id = blockIdx.x;
  const float* src;
  short* dst;
  int K, N, nT, kT;
  if (id < 432) {
    int m = id / 144, r = id % 144;
    src = qkv + m * DD; dst = lwq + m * DD;
    K = DMODEL; N = DMODEL; nT = r % 12; kT = r / 12;
  } else if (id < 576) {
    int r = id - 432;
    src = ao; dst = lwa;
    K = DMODEL; N = DMODEL; nT = r % 12; kT = r / 12;
  } else if (id < 1152) {
    int r = id - 576;
    src = w1; dst = lw1;
    K = DMODEL; N = FFDIM; nT = r % 48; kT = r / 48;
  } else {
    int r = id - 1152;
    src = w2; dst = lw2;
    K = FFDIM; N = DMODEL; nT = r % 12; kT = r / 12;
  }
  wtr_tile(src, dst, K, N, kT * 64, nT * 64, threadIdx.x, tile);
}

// ---------------------------------------------------------------------------
// V transpose: Vb [s][DM] bf16 -> VTg [h][d][s] bf16. grid=(64, 12).
// ---------------------------------------------------------------------------
__global__ __launch_bounds__(256) void vtr_kernel(const short* __restrict__ Vb,
                                                  short* __restrict__ VTg) {
  __shared__ short tile[64][65];
  const int s0 = blockIdx.x * 64, h = blockIdx.y;
  const int t = threadIdx.x;
  {
    int sr = t >> 2, dc = (t & 3) * 16;
    const short* p = Vb + (long)(s0 + sr) * DMODEL + h * 64 + dc;
    s8v a0 = *(const s8v*)p;
    s8v a1 = *(const s8v*)(p + 8);
#pragma unroll
    for (int j = 0; j < 8; ++j) tile[sr][dc + j] = a0[j];
#pragma unroll
    for (int j = 0; j < 8; ++j) tile[sr][dc + 8 + j] = a1[j];
  }
  __syncthreads();
  {
    int dr = t >> 2, sc = (t & 3) * 16;
    short* q = VTg + (long)(h * 64 + dr) * S_LEN + s0 + sc;
    s8v v0, v1;
#pragma unroll
    for (int j = 0; j < 8; ++j) v0[j] = tile[sc + j][dr];
#pragma unroll
    for (int j = 0; j < 8; ++j) v1[j] = tile[sc + 8 + j][dr];
    *(s8v*)q = v0;
    *(s8v*)(q + 8) = v1;
  }
}

// ---------------------------------------------------------------------------
// bf16 GEMM, 2-phase double-buffered, BK=32 (32KB LDS -> 4 blocks/CU).
// C[4096,N] = A[4096,K] @ Bt[N,K]^T. Chunk-XOR swizzled LDS.
// EPI: 0 none, 1 exact GELU, 2 scale (z==0) by QSCALE.
// OUT: 0 f32+bias, 1 bf16+bias, 2 bf16 partial no-bias (split-K: Koff=z*Klen).
// grid=(N/128, 32, Z), block=256 (4 waves). Requires gridDim.y==32, nwg%8==0.
// ---------------------------------------------------------------------------
template <int EPI, int OUT>
__global__ __launch_bounds__(256, 4) void bgemm_kernel(
    const short* __restrict__ A, const short* __restrict__ Bt,
    const float* __restrict__ bias, void* __restrict__ Cv,
    int N, int K, int Klen, long sB, long sBias, long sC) {
  __shared__ short As[2][128 * 32];
  __shared__ short Bs[2][128 * 32];
  const int t = threadIdx.x, lane = t & 63, w = t >> 6;
  const int lo = lane & 15, hi = lane >> 4;
  const int wm = (w >> 1) * 64, wn = (w & 1) * 64;

  // bijective XCD swizzle: y-chunks of 4 per XCD (gy==32)
  const int gx = gridDim.x;
  const int bid = blockIdx.x + gx * (blockIdx.y + 32 * blockIdx.z);
  const int xcd = bid & 7;
  const int jj_ = bid >> 3;
  const int bx = jj_ % gx;
  const int t2 = jj_ / gx;
  const int by = xcd * 4 + (t2 & 3);
  const int bz = t2 >> 2;

  const long bm = (long)by * 128;
  const int bn = bx * 128;
  Bt += (long)bz * sB;
  const long Koff = (OUT == 2) ? (long)bz * Klen : 0;

  f32x4 acc[4][4];
#pragma unroll
  for (int i = 0; i < 4; ++i)
#pragma unroll
    for (int j = 0; j < 4; ++j) {
      f32x4 zz = {0.f, 0.f, 0.f, 0.f};
      acc[i][j] = zz;
    }

  const int srow = lane >> 2;
  const int schunk = (lane & 3) ^ ((lane >> 3) & 3);
  const short* ga = A + (bm + srow) * (long)K + Koff + schunk * 8;
  const short* gb = Bt + ((long)bn + srow) * K + Koff + schunk * 8;

#define STAGE(buf, koff)                                                   \
  {                                                                        \
    _Pragma("unroll") for (int i = 0; i < 2; ++i) {                        \
      const int r0 = i * 64 + w * 16;                                      \
      gl_lds16(ga + (long)r0 * K + (koff), As[buf] + r0 * 32);             \
      gl_lds16(gb + (long)r0 * K + (koff), Bs[buf] + r0 * 32);             \
    }                                                                      \
  }

  STAGE(0, 0);
  __syncthreads();

  const int nt = Klen >> 5;
  const int rchunk = (hi ^ ((lo >> 1) & 3)) * 8;
  for (int kt = 0; kt < nt; ++kt) {
    const int cur = kt & 1;
    if (kt + 1 < nt) STAGE(cur ^ 1, (kt + 1) * 32);
    s8v af[4], bf[4];
#pragma unroll
    for (int mi = 0; mi < 4; ++mi)
      af[mi] = *(const s8v*)(As[cur] + (wm + mi * 16 + lo) * 32 + rchunk);
#pragma unroll
    for (int ni = 0; ni < 4; ++ni)
      bf[ni] = *(const s8v*)(Bs[cur] + (wn + ni * 16 + lo) * 32 + rchunk);
#pragma unroll
    for (int mi = 0; mi < 4; ++mi)
#pragma unroll
      for (int ni = 0; ni < 4; ++ni)
        acc[mi][ni] = mfma16(af[mi], bf[ni], acc[mi][ni]);
    __syncthreads();
  }
#undef STAGE

  const float sc = (EPI == 2 && bz == 0) ? QSCALE : 1.0f;
  float* Cf = (float*)Cv + (long)bz * sC;
  short* Cs = (short*)Cv + (long)bz * sC;
  const float* bp = bias + (long)bz * sBias;
#pragma unroll
  for (int mi = 0; mi < 4; ++mi)
#pragma unroll
    for (int ni = 0; ni < 4; ++ni) {
      int col = bn + wn + ni * 16 + lo;
      float bb = (OUT == 2) ? 0.f : bp[col];
#pragma unroll
      for (int jj = 0; jj < 4; ++jj) {
        long row = bm + wm + mi * 16 + hi * 4 + jj;
        float v = acc[mi][ni][jj] + bb;
        if (EPI == 2) v *= sc;
        if (EPI == 1) v = 0.5f * v * (1.0f + erff(v * 0.7071067811865476f));
        if (OUT == 0)
          Cf[row * N + col] = v;
        else
          Cs[row * N + col] = f2b(v);
      }
    }
}

// ---------------------------------------------------------------------------
// Banded flash attention v6: K and V^T both staged via gl_lds (V from the
// pre-transposed VTg [h][d][s]); dbuf prefetch at loop top; full-band fast
// path skips band compares; exp2-domain softmax; defer-max.
// grid=(64 qblocks, 12 heads), block=256 (4 waves x 16 q-rows).
// ---------------------------------------------------------------------------
__global__ __launch_bounds__(256) void attn_kernel(
    const short* __restrict__ Qb, const short* __restrict__ Kb,
    const short* __restrict__ VTg, const int* __restrict__ maskp,
    short* __restrict__ Ob) {
  __shared__ short Ks[2][64 * 64];  // [key][d], swizzled
  __shared__ short VT[2][64 * 64];  // [d][key], swizzled
  __shared__ short Pl[4][16 * 64];  // per-wave [q][key], swizzled

  const int t = threadIdx.x, lane = t & 63, w = t >> 6;
  const int lo = lane & 15, hi = lane >> 4;

  // XCD swizzle: 8 consecutive q-blocks per XCD
  const int bid = blockIdx.x + 64 * blockIdx.y;
  const int xcd = bid & 7, jb = bid >> 3;
  const int qb = xcd * 8 + (jb & 7), h = jb >> 3;

  const int q0 = qb * 64;
  const int qw = q0 + w * 16;
  short* Plw = Pl[w];

  s8v aq[2];
#pragma unroll
  for (int kg = 0; kg < 2; ++kg)
    aq[kg] = *(const s8v*)(Qb + (long)(qw + lo) * DMODEL + h * 64 + kg * 32 +
                           hi * 8);

  f32x4 o[4];
#pragma unroll
  for (int i = 0; i < 4; ++i) {
    f32x4 zz = {0.f, 0.f, 0.f, 0.f};
    o[i] = zz;
  }
  float rm[4], rl[4];
#pragma unroll
  for (int r = 0; r < 4; ++r) { rm[r] = -1e30f; rl[r] = 0.f; }

  const int kstart = max(0, q0 - WINR);
  const int kend = min(S_LEN, q0 + 64 + WINR);
  const int nt = (kend - kstart) >> 6;

  const int krow = lane >> 3;
  const int kxor = ((lane & 7) ^ krow) * 8;
  const long vrow = (long)(h * 64 + w * 16 + krow) * S_LEN;

#define STAGE_KV(buf, kt)                                                    \
  {                                                                          \
    _Pragma("unroll") for (int i = 0; i < 2; ++i) {                          \
      const int r0 = w * 16 + i * 8;                                         \
      gl_lds16(Kb + (long)((kt) + r0 + krow) * DMODEL + h * 64 + kxor,       \
               Ks[buf] + r0 * 64);                                           \
      gl_lds16(VTg + vrow + (long)i * 8 * S_LEN + (kt) + kxor,               \
               VT[buf] + r0 * 64);                                           \
    }                                                                        \
  }

  STAGE_KV(0, kstart);
  __syncthreads();

  for (int ti = 0; ti < nt; ++ti) {
    const int kt = kstart + ti * 64;
    const int cur = ti & 1;
    if (ti + 1 < nt) STAGE_KV(cur ^ 1, kt + 64);

    const bool active = (kt + 63 >= qw - WINR) && (kt <= qw + 15 + WINR);
    if (active) {
      f32x4 sacc[4];
#pragma unroll
      for (int i = 0; i < 4; ++i) {
        f32x4 zz = {0.f, 0.f, 0.f, 0.f};
        sacc[i] = zz;
      }
#pragma unroll
      for (int ni = 0; ni < 4; ++ni)
#pragma unroll
        for (int kg = 0; kg < 2; ++kg) {
          const int chunk = (kg * 4 + hi) ^ (lo & 7);
          s8v bk = *(const s8v*)(Ks[cur] + (ni * 16 + lo) * 64 + chunk * 8);
          sacc[ni] = mfma16(aq[kg], bk, sacc[ni]);
        }

      int mval[4];
#pragma unroll
      for (int ni = 0; ni < 4; ++ni) mval[ni] = maskp[kt + ni * 16 + lo];

      // full-band fast path: all 64 keys in-band for every row of this wave
      const bool fullband = (kt >= qw + 15 - WINR) && (kt + 63 <= qw + WINR);

      float m0[4];
      if (fullband) {
#pragma unroll
        for (int jj = 0; jj < 4; ++jj) {
          float mm = -1e30f;
#pragma unroll
          for (int ni = 0; ni < 4; ++ni) {
            float sv = (mval[ni] != 0) ? sacc[ni][jj] : -1e30f;
            sacc[ni][jj] = sv;
            mm = fmaxf(mm, sv);
          }
          mm = fmaxf(mm, __shfl_xor(mm, 1));
          mm = fmaxf(mm, __shfl_xor(mm, 2));
          mm = fmaxf(mm, __shfl_xor(mm, 4));
          mm = fmaxf(mm, __shfl_xor(mm, 8));
          m0[jj] = mm;
        }
      } else {
#pragma unroll
        for (int jj = 0; jj < 4; ++jj) {
          const int qg = qw + hi * 4 + jj;
          float mm = -1e30f;
#pragma unroll
          for (int ni = 0; ni < 4; ++ni) {
            int kg = kt + ni * 16 + lo;
            bool val = (kg >= qg - WINR) && (kg <= qg + WINR) && (mval[ni] != 0);
            float sv = val ? sacc[ni][jj] : -1e30f;
            sacc[ni][jj] = sv;
            mm = fmaxf(mm, sv);
          }
          mm = fmaxf(mm, __shfl_xor(mm, 1));
          mm = fmaxf(mm, __shfl_xor(mm, 2));
          mm = fmaxf(mm, __shfl_xor(mm, 4));
          mm = fmaxf(mm, __shfl_xor(mm, 8));
          m0[jj] = mm;
        }
      }

      bool skipf = true;
#pragma unroll
      for (int jj = 0; jj < 4; ++jj) skipf = skipf && (m0[jj] - rm[jj] <= THR2);

      if (__all(skipf)) {
#pragma unroll
        for (int jj = 0; jj < 4; ++jj) {
          float ts = 0.f;
#pragma unroll
          for (int ni = 0; ni < 4; ++ni) {
            float sv = sacc[ni][jj];
            float p = (sv > -1e29f) ? exp2f(sv - rm[jj]) : 0.f;
            sacc[ni][jj] = p;
            ts += p;
          }
          ts += __shfl_xor(ts, 1);
          ts += __shfl_xor(ts, 2);
          ts += __shfl_xor(ts, 4);
          ts += __shfl_xor(ts, 8);
          rl[jj] += ts;
        }
      } else {
#pragma unroll
        for (int jj = 0; jj < 4; ++jj) {
          float mnew = fmaxf(rm[jj], m0[jj]);
          float scl = exp2f(rm[jj] - mnew);
          rm[jj] = mnew;
          float ts = 0.f;
#pragma unroll
          for (int ni = 0; ni < 4; ++ni) {
            float sv = sacc[ni][jj];
            float p = (sv > -1e29f) ? exp2f(sv - mnew) : 0.f;
            sacc[ni][jj] = p;
            ts += p;
          }
          ts += __shfl_xor(ts, 1);
          ts += __shfl_xor(ts, 2);
          ts += __shfl_xor(ts, 4);
          ts += __shfl_xor(ts, 8);
          rl[jj] = rl[jj] * scl + ts;
#pragma unroll
          for (int di = 0; di < 4; ++di) o[di][jj] *= scl;
        }
      }

#pragma unroll
      for (int jj = 0; jj < 4; ++jj) {
        const int qr = hi * 4 + jj;
#pragma unroll
        for (int ni = 0; ni < 4; ++ni) {
          const int chunk = (ni * 2 + (lo >> 3)) ^ (qr & 7);
          Plw[qr * 64 + chunk * 8 + (lo & 7)] = f2b(sacc[ni][jj]);
        }
      }

      s8v ap[2];
#pragma unroll
      for (int kg = 0; kg < 2; ++kg) {
        const int chunk = (kg * 4 + hi) ^ (lo & 7);
        ap[kg] = *(const s8v*)(Plw + lo * 64 + chunk * 8);
      }
#pragma unroll
      for (int di = 0; di < 4; ++di)
#pragma unroll
        for (int kg = 0; kg < 2; ++kg) {
          const int chunk = (kg * 4 + hi) ^ (lo & 7);
          s8v bv = *(const s8v*)(VT[cur] + (di * 16 + lo) * 64 + chunk * 8);
          o[di] = mfma16(ap[kg], bv, o[di]);
        }
    }
    __syncthreads();
  }
#undef STAGE_KV

#pragma unroll
  for (int di = 0; di < 4; ++di)
#pragma unroll
    for (int jj = 0; jj < 4; ++jj) {
      long row = qw + hi * 4 + jj;
      Ob[row * DMODEL + h * 64 + di * 16 + lo] = f2b(o[di][jj] / rl[jj]);
    }
}

// ---------------------------------------------------------------------------
// Embedding + LayerNorm, dual output (f32 X + bf16 Xb). grid=4096, block=256.
// ---------------------------------------------------------------------------
__global__ __launch_bounds__(256) void embed_ln_kernel(
    const int* __restrict__ tok, const float* __restrict__ wemb,
    const float* __restrict__ pemb, const float* __restrict__ gs,
    const float* __restrict__ gb, float* __restrict__ X,
    short* __restrict__ Xb) {
  __shared__ float sm1[4], sm2[4];
  const int row = blockIdx.x;
  const int tk = tok[row];
  float v[3];
  float s = 0.f, q = 0.f;
#pragma unroll
  for (int i = 0; i < 3; ++i) {
    int c = threadIdx.x + i * 256;
    float x = wemb[(long)tk * DMODEL + c] + pemb[(long)(row + 2) * DMODEL + c];
    v[i] = x;
    s += x;
    q += x * x;
  }
#pragma unroll
  for (int off = 32; off; off >>= 1) {
    s += __shfl_down(s, off);
    q += __shfl_down(q, off);
  }
  int w = threadIdx.x >> 6;
  if ((threadIdx.x & 63) == 0) { sm1[w] = s; sm2[w] = q; }
  __syncthreads();
  s = sm1[0] + sm1[1] + sm1[2] + sm1[3];
  q = sm2[0] + sm2[1] + sm2[2] + sm2[3];
  float mu = s * (1.f / DMODEL);
  float var = q * (1.f / DMODEL) - mu * mu;
  float inv = rsqrtf(var + 1e-5f);
#pragma unroll
  for (int i = 0; i < 3; ++i) {
    int c = threadIdx.x + i * 256;
    float y = (v[i] - mu) * inv * gs[c] + gb[c];
    X[(long)row * DMODEL + c] = y;
    Xb[(long)row * DMODEL + c] = f2b(y);
  }
}

// ---------------------------------------------------------------------------
// X = LayerNorm(X + P0b + P1b + bias), partials bf16. grid=4096.
// ---------------------------------------------------------------------------
__global__ __launch_bounds__(256) void resln2_kernel(
    float* __restrict__ X, const short* __restrict__ P0b,
    const short* __restrict__ P1b, const float* __restrict__ bias,
    const float* __restrict__ gs, const float* __restrict__ gb,
    short* __restrict__ Xb) {
  __shared__ float sm1[4], sm2[4];
  const int row = blockIdx.x;
  float v[3];
  float s = 0.f, q = 0.f;
#pragma unroll
  for (int i = 0; i < 3; ++i) {
    int c = threadIdx.x + i * 256;
    long ix = (long)row * DMODEL + c;
    float x = X[ix] + b2f(P0b[ix]) + b2f(P1b[ix]) + bias[c];
    v[i] = x;
    s += x;
    q += x * x;
  }
#pragma unroll
  for (int off = 32; off; off >>= 1) {
    s += __shfl_down(s, off);
    q += __shfl_down(q, off);
  }
  int w = threadIdx.x >> 6;
  if ((threadIdx.x & 63) == 0) { sm1[w] = s; sm2[w] = q; }
  __syncthreads();
  s = sm1[0] + sm1[1] + sm1[2] + sm1[3];
  q = sm2[0] + sm2[1] + sm2[2] + sm2[3];
  float mu = s * (1.f / DMODEL);
  float var = q * (1.f / DMODEL) - mu * mu;
  float inv = rsqrtf(var + 1e-5f);
#pragma unroll
  for (int i = 0; i < 3; ++i) {
    int c = threadIdx.x + i * 256;
    float y = (v[i] - mu) * inv * gs[c] + gb[c];
    X[(long)row * DMODEL + c] = y;
    Xb[(long)row * DMODEL + c] = f2b(y);
  }
}

// ---------------------------------------------------------------------------
// out[row] = dot(H3[row,:512] (bf16), w4[:,0] (f32)) + b4[0].
// ---------------------------------------------------------------------------
__global__ __launch_bounds__(256) void cls_final_kernel(
    const short* __restrict__ Hh, const float* __restrict__ w4,
    const float* __restrict__ b4, float* __restrict__ out) {
  const int w = threadIdx.x >> 6, lane = threadIdx.x & 63;
  const int row = blockIdx.x * 4 + w;
  float s = 0.f;
#pragma unroll
  for (int j = 0; j < 8; ++j) {
    int k = lane + j * 64;
    s += b2f(Hh[(long)row * 512 + k]) * w4[k * 2];
  }
#pragma unroll
  for (int off = 32; off; off >>= 1) s += __shfl_down(s, off);
  if (lane == 0) out[row] = s + b4[0];
}

// ---------------------------------------------------------------------------
extern "C" void kernel_launch(void* const* d_in, const int* in_sizes, int n_in,
                              void* d_out, int out_size, void* d_ws,
                              size_t ws_size, hipStream_t stream) {
  const int* essay = (const int*)d_in[0];
  const float* wemb = (const float*)d_in[1];
  const float* pemb = (const float*)d_in[2];
  const float* eln_s = (const float*)d_in[3];
  const float* eln_b = (const float*)d_in[4];
  const float* qkv_w = (const float*)d_in[5];
  const float* qkv_b = (const float*)d_in[6];
  const float* aow = (const float*)d_in[7];
  const float* aob = (const float*)d_in[8];
  const float* aln_s = (const float*)d_in[9];
  const float* aln_b = (const float*)d_in[10];
  const float* w1 = (const float*)d_in[11];
  const float* b1 = (const float*)d_in[12];
  const float* w2 = (const float*)d_in[13];
  const float* b2 = (const float*)d_in[14];
  const float* fln_s = (const float*)d_in[15];
  const float* fln_b = (const float*)d_in[16];
  const float* c1w = (const float*)d_in[17];
  const float* c1b = (const float*)d_in[18];
  const float* c2w = (const float*)d_in[19];
  const float* c2b = (const float*)d_in[20];
  const float* c3w = (const float*)d_in[21];
  const float* c3b = (const float*)d_in[22];
  const float* c4w = (const float*)d_in[23];
  const float* c4b = (const float*)d_in[24];

  const long SD = (long)S_LEN * DMODEL;
  const long SF = (long)S_LEN * FFDIM;
  const long SH = (long)S_LEN * 512;
  const long DD = (long)DMODEL * DMODEL;
  const long DF = (long)DMODEL * FFDIM;

  float* X = (float*)d_ws;
  float* P0 = X + SD;           // holds 2x bf16 split-K partials (2*SD shorts)
  float* P1 = P0 + SD;          // holds VTg (SD shorts) — disjoint lifetime
  short* P0b = (short*)P0;
  short* P1b = P0b + SD;
  short* VTg = (short*)P1;
  short* lwq = (short*)(P1 + SD);
  short* lwa = lwq + 3 * DD;
  short* lw1 = lwa + DD;
  short* lw2 = lw1 + DF;
  short* c1T = lw2 + DF;
  short* c2T = c1T + (long)DMODEL * 512;
  short* c3T = c2T + 512L * 512;
  short* Xb = c3T + 512L * 512;
  short* QKVb = Xb + SD;
  short* T1b = QKVb + 3 * SD;
  short* T2b = T1b + SD;
  short* H1 = T2b + SF;
  short* H2 = H1 + SH;
  short* H3 = H2 + SH;
  const long needed = (char*)(H3 + SH) - (char*)d_ws;
  if (ws_size < (size_t)needed) return;

  const int* maskp = essay + S_LEN;

  embed_ln_kernel<<<S_LEN, 256, 0, stream>>>(essay, wemb, pemb, eln_s, eln_b, X,
                                             Xb);

  for (int l = 0; l < NLAYER; ++l) {
    wtr_layer_kernel<<<1728, 256, 0, stream>>>(
        qkv_w + l * 3 * DD, aow + l * DD, w1 + l * DF, w2 + l * DF, lwq, lwa,
        lw1, lw2);

    bgemm_kernel<2, 1><<<dim3(6, 32, 3), 256, 0, stream>>>(
        Xb, lwq, qkv_b + (long)l * 3 * DMODEL, QKVb, DMODEL, DMODEL, DMODEL, DD,
        DMODEL, SD);
    vtr_kernel<<<dim3(64, 12), 256, 0, stream>>>(QKVb + 2 * SD, VTg);
    attn_kernel<<<dim3(64, 12), 256, 0, stream>>>(QKVb, QKVb + SD, VTg, maskp,
                                                  T1b);
    // attn-out projection: split-K x2 -> bf16 partials P0b,P1b
    bgemm_kernel<0, 2><<<dim3(6, 32, 2), 256, 0, stream>>>(
        T1b, lwa, aob, P0b, DMODEL, DMODEL, 384, 0, 0, SD);
    resln2_kernel<<<S_LEN, 256, 0, stream>>>(X, P0b, P1b,
                                             aob + (long)l * DMODEL,
                                             aln_s + (long)l * DMODEL,
                                             aln_b + (long)l * DMODEL, Xb);
    bgemm_kernel<1, 1><<<dim3(24, 32, 1), 256, 0, stream>>>(
        Xb, lw1, b1 + (long)l * FFDIM, T2b, FFDIM, DMODEL, DMODEL, 0, 0, 0);
    // FFN down-projection: split-K x2 -> bf16 partials P0b,P1b
    bgemm_kernel<0, 2><<<dim3(6, 32, 2), 256, 0, stream>>>(
        T2b, lw2, b2, P0b, DMODEL, FFDIM, 1536, 0, 0, SD);
    resln2_kernel<<<S_LEN, 256, 0, stream>>>(X, P0b, P1b,
                                             b2 + (long)l * DMODEL,
                                             fln_s + (long)l * DMODEL,
                                             fln_b + (long)l * DMODEL, Xb);
  }

  wtr_kernel<<<dim3(8, 12), 256, 0, stream>>>(c1w, c1T, DMODEL, 512);
  wtr_kernel<<<dim3(8, 8), 256, 0, stream>>>(c2w, c2T, 512, 512);
  wtr_kernel<<<dim3(8, 8), 256, 0, stream>>>(c3w, c3T, 512, 512);

  bgemm_kernel<0, 1><<<dim3(4, 32, 1), 256, 0, stream>>>(
      Xb, c1T, c1b, H1, 512, DMODEL, DMODEL, 0, 0, 0);
  bgemm_kernel<0, 1><<<dim3(4, 32, 1), 256, 0, stream>>>(H1, c2T, c2b, H2, 512,
                                                         512, 512, 0, 0, 0);
  bgemm_kernel<0, 1><<<dim3(4, 32, 1), 256, 0, stream>>>(H2, c3T, c3b, H3, 512,
                                                         512, 512, 0, 0, 0);
  cls_final_kernel<<<S_LEN / 4, 256, 0, stream>>>(H3, c4w, c4b, (float*)d_out);
}